// Round 10
// baseline (203.021 us; speedup 1.0000x reference)
//
#include <hip/hip_runtime.h>

#define NROI 1000
#define NCLS 81
#define NB   8
#define NLANE (NB*NCLS)        // 648 = 8 XCDs * 81
#define MAXM 1024
#define MAXKEEP 200
#define SCORE_T 0.5f
#define NT 512
#define NW 8                   // waves per block
#define HBITS 13
#define HSIZE (1<<HBITS)       // 8192 merge buckets
#define SCAP 1024

typedef unsigned long long u64;
typedef unsigned int u32;

// --- register-broadcast helpers (VALU v_readlane; no LDS pipe, no mem latency) ---
__device__ __forceinline__ float rlf(float v, int i) {
  return __int_as_float(__builtin_amdgcn_readlane(__float_as_int(v), i));
}
__device__ __forceinline__ u64 rl64(u64 v, int i) {
  u32 lo = (u32)__builtin_amdgcn_readlane((int)(u32)(v & 0xFFFFFFFFull), i);
  u32 hi = (u32)__builtin_amdgcn_readlane((int)(u32)(v >> 32), i);
  return ((u64)hi << 32) | lo;
}

// --- exact-order helpers (no FMA contraction; must match f32 numpy reference) ---

__device__ __forceinline__ void decode_box(const float* __restrict__ roi,
                                           const float* __restrict__ dl,
                                           float& oy1, float& ox1,
                                           float& oy2, float& ox2) {
#pragma clang fp contract(off)
  float y1 = roi[0], x1 = roi[1], y2 = roi[2], x2 = roi[3];
  float h = y2 - y1;
  float w = x2 - x1;
  float cy = y1 + 0.5f * h;
  float cx = x1 + 0.5f * w;
  float d0 = dl[0] * 0.1f;
  float d1 = dl[1] * 0.1f;
  float d2 = dl[2] * 0.2f;
  float d3 = dl[3] * 0.2f;
  float ncy = d0 * h + cy;
  float ncx = d1 * w + cx;
  float nh = expf(d2) * h;
  float nw = expf(d3) * w;
  oy1 = ncy - 0.5f * nh;
  ox1 = ncx - 0.5f * nw;
  oy2 = ncy + 0.5f * nh;
  ox2 = ncx + 0.5f * nw;
}

__device__ __forceinline__ float area_f(float4 bx) {
#pragma clang fp contract(off)
  return (bx.z - bx.x) * (bx.w - bx.y);
}

// EXACT equivalent of: fl32(inter/den) > 0.5 (RNE), den>0 — proof in R6/R7:
// collapses to (inter+inter) > den in plain f32.
__device__ __forceinline__ bool hit_f(float4 bi, float ia, float4 bj, float ja) {
#pragma clang fp contract(off)
  float yy1 = fmaxf(bi.x, bj.x);
  float xx1 = fmaxf(bi.y, bj.y);
  float yy2 = fminf(bi.z, bj.z);
  float xx2 = fminf(bi.w, bj.w);
  float ih = fmaxf(yy2 - yy1, 0.0f);
  float iw = fmaxf(xx2 - xx1, 0.0f);
  float inter = ih * iw;
  float den = ia + ja;
  den = den - inter;
  den = den + 1e-8f;
  return (inter + inter) > den;
}

// key packing: [63:32] score bits, [31:15] (131071-flat) so lower flat wins,
//              [14:5] n (payload only), [4:0] zero. Empty slot = 0.
__device__ __forceinline__ u64 pack_key(u32 sbits, int flat, int n) {
  return ((u64)sbits << 32) | ((u64)(131071 - flat) << 15) | ((u64)n << 5);
}

// --- kernel 1: background rows (argmax over classes == 0), wave per row ---
__global__ __launch_bounds__(256) void bg_kernel(const float* __restrict__ probs,
                                                 int* __restrict__ bg) {
  int row = blockIdx.x * 4 + (threadIdx.x >> 6);
  int lane = threadIdx.x & 63;
  if (row >= NB * NROI) return;
  const float* p = probs + (size_t)row * NCLS;
  float m = -1e30f;
  for (int idx = 1 + lane; idx < NCLS; idx += 64) m = fmaxf(m, p[idx]);
  for (int off = 32; off; off >>= 1) m = fmaxf(m, __shfl_xor(m, off));
  if (lane == 0) bg[row] = (p[0] >= m) ? 1 : 0;  // argmax==0 iff p0 >= all others
}

// --- kernel 2 (fused): gather + stripe rank-sort + decode + readlane greedy NMS ---
__global__ __launch_bounds__(NT) void gather_nms_kernel(
    const float* __restrict__ roi, const float* __restrict__ deltas,
    const float* __restrict__ probs, const int* __restrict__ bg,
    int* __restrict__ keep_count, u64* __restrict__ lane_key,
    int* __restrict__ bhist) {
  // XCD swizzle: 648 = 8*81; dispatch idx%8 = XCD -> XCD x owns batch x entirely
  int lane = (blockIdx.x % 8) * NCLS + blockIdx.x / 8;
  int b = lane / NCLS, c = lane % NCLS;
  int tid = threadIdx.x;
  int w = tid >> 6, l = tid & 63;

  // smem: [0,16K) sbox (alias: skeyU in [0,8K), dead after sort)
  //       [16K,24K) hmask; [24K,32K) skey (sorted, live to the end)
  __shared__ alignas(16) char smem[32768];
  float4* sbox  = (float4*)smem;
  u64*    skeyU = (u64*)smem;
  u64*    hmask = (u64*)(smem + 16384);
  u64*    skey  = (u64*)(smem + 24576);
  __shared__ u64 keepmask[16];
  __shared__ u64 chunk_kept;
  __shared__ int scount, segbase[16];

  if (tid == 0) scount = 0;
  __syncthreads();

  // --- gather: score > 0.5 && !bg (ballot-aggregated append; M <= 1000) ---
  for (int base_n = 0; base_n < NROI; base_n += NT) {
    int n = base_n + tid;
    bool cand = false;
    float s = 0.0f;
    if (n < NROI) {
      int row = b * NROI + n;
      s = probs[(size_t)row * NCLS + c];
      cand = (s > SCORE_T) && (bg[row] == 0);
    }
    u64 bal = __ballot(cand);
    int wb = 0;
    if (l == 0) wb = atomicAdd(&scount, (int)__popcll(bal));
    wb = __shfl(wb, 0);
    if (cand) {
      int off = (int)__popcll(bal & ((1ull << l) - 1ull));
      skeyU[wb + off] = ((u64)__float_as_uint(s) << 32) | (u64)(0xFFFFFFFFu - (u32)n);
    }
  }
  __syncthreads();
  int M = scount;                // <= 1000
  int S = (M + 63) >> 6;         // key stripes
  int nchunks = S;

  // pad keys to stripe boundary (0-key never beats a valid key)
  for (int p = M + tid; p < (S << 6); p += NT) skeyU[p] = 0ull;
  if (tid < 16) {                // keep bitmask init: bits p < M set
    int rem = M - (tid << 6);
    keepmask[tid] = (rem >= 64) ? ~0ull : ((rem <= 0) ? 0ull : ((1ull << rem) - 1ull));
  }
  __syncthreads();

  // --- rank sort via coalesced stripes + readlane broadcast (keys unique) ---
  if (M <= NT) {                 // block-uniform fast path: 1 key/thread
    u64 k0 = (tid < M) ? skeyU[tid] : 0ull;
    int r0 = 0;
    for (int s = 0; s < S; ++s) {
      u64 strip = skeyU[(s << 6) + l];   // coalesced b64, once per 64 keys
#pragma unroll
      for (int q = 0; q < 64; ++q) r0 += (rl64(strip, q) > k0);
    }
    if (tid < M) skey[r0] = k0;
  } else {                       // 2 keys/thread
    u64 k0 = skeyU[tid];
    u64 k1 = (tid + NT < M) ? skeyU[tid + NT] : 0ull;
    int r0 = 0, r1 = 0;
    for (int s = 0; s < S; ++s) {
      u64 strip = skeyU[(s << 6) + l];
#pragma unroll
      for (int q = 0; q < 64; ++q) {
        u64 kq = rl64(strip, q);
        r0 += (kq > k0);
        r1 += (kq > k1);
      }
    }
    skey[r0] = k0;
    if (tid + NT < M) skey[r1] = k1;
  }
  __syncthreads();   // all skeyU reads done; skey ready

  // --- decode sorted candidates into sbox (overwrites dead skeyU region) ---
  for (int p = tid; p < M; p += NT) {
    u64 k = skey[p];
    u32 n = 0xFFFFFFFFu - (u32)(k & 0xFFFFFFFFull);
    int row = b * NROI + (int)n;
    float by1, bx1, by2, bx2;
    decode_box(roi + (size_t)row * 4, deltas + ((size_t)row * NCLS + c) * 4,
               by1, bx1, by2, bx2);
    sbox[p] = make_float4(by1, bx1, by2, bx2);
  }

  // --- chunked greedy NMS: j-per-lane map, chunk boxes via readlane ---
  for (int ck = 0; ck < nchunks; ++ck) {
    int start = ck << 6;
    __syncthreads();   // A: decode done / prev step3 done reading hmask

    // lane l's chunk box (broadcast source for the whole wave)
    float4 bs = sbox[start + l];         // coalesced; garbage beyond M masked later
    float sy1 = bs.x, sx1 = bs.y, sy2 = bs.z, sx2 = bs.w;
    float sa = area_f(bs);
    u64 hm_self = 0;

    // map: wave w owns j-tiles g = ck+w, ck+w+8, ... ; lane l owns j = g*64+l
    for (int g = ck + w; g < nchunks; g += NW) {
      int j = (g << 6) + l;
      float4 bj = sbox[j];               // coalesced b128, once per 64 pairs
      float ja = area_f(bj);
      u64 hm = 0;
#pragma unroll
      for (int i = 0; i < 64; ++i) {     // chunk box i from registers (readlane)
        float4 bi = make_float4(rlf(sy1, i), rlf(sx1, i), rlf(sy2, i), rlf(sx2, i));
        float ia = rlf(sa, i);
        if (hit_f(bi, ia, bj, ja)) hm |= (1ull << i);
      }
      if (g == ck) hm_self = hm;         // wave 0's own row stays in registers
      else hmask[j] = hm;
    }

    // resolve (wave 0, immediately — uses only its registers + keepmask[ck])
    if (w == 0) {
      u64 kw = keepmask[ck];
      bool alive = (kw >> l) & 1;
      u64 mask = alive ? (hm_self & ((1ull << l) - 1ull)) : 0ull;
      u64 rem = ~__ballot(alive);
      for (int i = 0; i < 63; ++i) {
        if (!((rem >> i) & 1)) rem |= __ballot((mask >> i) & 1);  // uniform branch
      }
      bool kept = alive && !((rem >> l) & 1);
      u64 km = __ballot(kept);
      if (l == 0) { keepmask[ck] = km; chunk_kept = km; }
    }
    __syncthreads();   // B: hmask + km ready

    // step 3: cross-chunk suppression; one 64-j group per wave round-robin
    u64 km = chunk_kept;
    for (int g = ck + 1 + w; g < nchunks; g += NW) {
      u64 kw = keepmask[g];
      if (kw == 0ull) continue;          // wave-uniform
      int j = (g << 6) + l;              // kw bit l set implies j < M
      bool supp = ((kw >> l) & 1) && (hmask[j] & km);
      u64 sb = __ballot(supp);
      if (l == 0 && sb) keepmask[g] = kw & ~sb;
    }
  }
  __syncthreads();

  // --- parallel compaction + fused per-batch 13-bit histogram ---
  if (tid < 16) {
    int acc = 0;
    for (int i = 0; i < tid; ++i) acc += (int)__popcll(keepmask[i]);
    segbase[tid] = acc;
  }
  __syncthreads();
  int total = segbase[15] + (int)__popcll(keepmask[15]);
  for (int s = 0; s < 2; ++s) {
    int seg = (w << 1) + s;
    u64 word = keepmask[seg];
    int p = (seg << 6) + l;
    if ((word >> l) & 1) {
      int rank = segbase[seg] + (int)__popcll(word & ((1ull << l) - 1ull));
      if (rank < MAXKEEP) {
        u64 k = skey[p];
        u32 sbits = (u32)(k >> 32);
        int n = (int)(0xFFFFFFFFu - (u32)(k & 0xFFFFFFFFull));
        lane_key[(size_t)lane * MAXKEEP + rank] = pack_key(sbits, c * NROI + p, n);
        atomicAdd(&bhist[b * HSIZE + (int)((sbits >> 10) & (HSIZE - 1))], 1);
      }
    }
  }
  if (tid == 0) keep_count[lane] = min(total, MAXKEEP);
}

// --- kernel 3: per-batch parallel top-200 (radix-select + bitonic), exact order ---
__global__ __launch_bounds__(512) void merge_kernel(
    const float* __restrict__ roi, const float* __restrict__ deltas,
    const int* __restrict__ keep_count, const u64* __restrict__ lane_key,
    const int* __restrict__ bhist,
    float* __restrict__ out_b, float* __restrict__ out_c, float* __restrict__ out_s) {
  int b = blockIdx.x;    // 8 blocks; idx%8 = XCD that produced batch b's keys
  int tid = threadIdx.x;

  __shared__ int hist[HSIZE];
  __shared__ int csum[256];
  __shared__ int cnts[NCLS];
  __shared__ int tb_sh, scnt_sh;
  __shared__ u64 surv[SCAP];

  for (int i = tid; i < HSIZE; i += 512) hist[i] = bhist[b * HSIZE + i];
  for (int i = tid; i < NCLS; i += 512) cnts[i] = keep_count[b * NCLS + i];
  if (tid == 0) { tb_sh = 0; scnt_sh = 0; }
  __syncthreads();

  // suffix sums; find tb = max bucket with sufsum >= 200 (0 if total < 200)
  int base = tid * 32;
  if (tid < 256) {
    int psum = 0;
    for (int i = 0; i < 32; ++i) psum += hist[base + i];
    csum[tid] = psum;
  }
  __syncthreads();
  if (tid == 0) {
    int acc = 0;
    for (int t = 255; t >= 0; --t) { acc += csum[t]; csum[t] = acc; }
  }
  __syncthreads();
  if (tid < 256) {
    int acc = (tid < 255) ? csum[tid + 1] : 0;
    int local_tb = -1;
    for (int i = 31; i >= 0; --i) {
      acc += hist[base + i];
      if (acc >= MAXKEEP && local_tb < 0) local_tb = base + i;
    }
    if (local_tb >= 0) atomicMax(&tb_sh, local_tb);
  }
  __syncthreads();
  int tb = tb_sh;

  // gather survivors (all keys in buckets >= tb; superset of exact top-200)
  for (int s = tid; s < NCLS * MAXKEEP; s += 512) {
    int c = s / MAXKEEP, h = s % MAXKEEP;
    if (h < cnts[c]) {
      u64 k = lane_key[((size_t)(b * NCLS + c)) * MAXKEEP + h];
      u32 sb = (u32)(k >> 32);
      if ((int)((sb >> 10) & (HSIZE - 1)) >= tb) {
        int pos = atomicAdd(&scnt_sh, 1);
        if (pos < SCAP) surv[pos] = k;
      }
    }
  }
  __syncthreads();
  int scnt = min(scnt_sh, SCAP);
  int size = 2;
  while (size < scnt) size <<= 1;
  for (int i = scnt + tid; i < size; i += 512) surv[i] = 0ull;
  __syncthreads();

  // bitonic sort descending by full key (score desc, flat asc)
  for (int k2 = 2; k2 <= size; k2 <<= 1) {
    for (int j = k2 >> 1; j > 0; j >>= 1) {
      for (int i = tid; i < size; i += 512) {
        int ixj = i ^ j;
        if (ixj > i) {
          u64 a = surv[i], bb = surv[ixj];
          bool swp = ((i & k2) == 0) ? (a < bb) : (a > bb);
          if (swp) { surv[i] = bb; surv[ixj] = a; }
        }
      }
      __syncthreads();
    }
  }

  // decode + write top-200 in parallel; zero-fill the rest
  for (int t = tid; t < MAXKEEP; t += 512) {
    size_t ob = ((size_t)b * MAXKEEP + t) * 4;
    if (t < scnt) {
      u64 k = surv[t];
      int flat = 131071 - (int)((k >> 15) & 0x1FFFF);
      int c = flat / NROI;
      int n = (int)((k >> 5) & 0x3FF);
      int row = b * NROI + n;
      float by1, bx1, by2, bx2;
      decode_box(roi + (size_t)row * 4, deltas + ((size_t)row * NCLS + c) * 4,
                 by1, bx1, by2, bx2);
      out_b[ob + 0] = fminf(fmaxf(by1, 0.0f), 1.0f);
      out_b[ob + 1] = fminf(fmaxf(bx1, 0.0f), 1.0f);
      out_b[ob + 2] = fminf(fmaxf(by2, 0.0f), 1.0f);
      out_b[ob + 3] = fminf(fmaxf(bx2, 0.0f), 1.0f);
      out_c[b * MAXKEEP + t] = (float)c;
      out_s[b * MAXKEEP + t] = __uint_as_float((u32)(k >> 32));
    } else {
      out_b[ob + 0] = 0.0f; out_b[ob + 1] = 0.0f;
      out_b[ob + 2] = 0.0f; out_b[ob + 3] = 0.0f;
      out_c[b * MAXKEEP + t] = 0.0f;
      out_s[b * MAXKEEP + t] = 0.0f;
    }
  }
}

extern "C" void kernel_launch(void* const* d_in, const int* in_sizes, int n_in,
                              void* d_out, int out_size, void* d_ws, size_t ws_size,
                              hipStream_t stream) {
  const float* roi    = (const float*)d_in[0];  // [8,1000,4]
  const float* deltas = (const float*)d_in[1];  // [8,1000,324]
  const float* probs  = (const float*)d_in[2];  // [8,1000,81]

  char* ws = (char*)d_ws;
  int* bg         = (int*)(ws);                   // 32000 B
  int* keep_count = (int*)(ws + 32768);           // 2592 B
  int* bhist      = (int*)(ws + 40960);           // 8*8192*4 = 262144 B
  u64* lane_key   = (u64*)(ws + 40960 + 262144);  // 648*200*8 = 1,036,800 B

  float* out_b = (float*)d_out;                 // [8,200,4]
  float* out_c = out_b + NB * MAXKEEP * 4;      // [8,200]
  float* out_s = out_c + NB * MAXKEEP;          // [8,200]

  hipMemsetAsync(bhist, 0, NB * HSIZE * sizeof(int), stream);
  bg_kernel<<<(NB * NROI + 3) / 4, 256, 0, stream>>>(probs, bg);
  gather_nms_kernel<<<NLANE, NT, 0, stream>>>(roi, deltas, probs, bg,
                                              keep_count, lane_key, bhist);
  merge_kernel<<<NB, 512, 0, stream>>>(roi, deltas, keep_count, lane_key, bhist,
                                       out_b, out_c, out_s);
}

// Round 11
// 159.867 us; speedup vs baseline: 1.2699x; 1.2699x over previous
//
#include <hip/hip_runtime.h>

#define NROI 1000
#define NCLS 81
#define NB   8
#define NLANE (NB*NCLS)        // 648 = 8 XCDs * 81
#define MAXM 1024
#define MAXKEEP 200
#define SCORE_T 0.5f
#define NT 512
#define NW 8                   // waves per block
#define HBITS 13
#define HSIZE (1<<HBITS)       // 8192 merge buckets
#define SCAP 1024

typedef unsigned long long u64;
typedef unsigned int u32;

// --- exact-order helpers (no FMA contraction; must match f32 numpy reference) ---

__device__ __forceinline__ void decode_box(const float* __restrict__ roi,
                                           const float* __restrict__ dl,
                                           float& oy1, float& ox1,
                                           float& oy2, float& ox2) {
#pragma clang fp contract(off)
  float y1 = roi[0], x1 = roi[1], y2 = roi[2], x2 = roi[3];
  float h = y2 - y1;
  float w = x2 - x1;
  float cy = y1 + 0.5f * h;
  float cx = x1 + 0.5f * w;
  float d0 = dl[0] * 0.1f;
  float d1 = dl[1] * 0.1f;
  float d2 = dl[2] * 0.2f;
  float d3 = dl[3] * 0.2f;
  float ncy = d0 * h + cy;
  float ncx = d1 * w + cx;
  float nh = expf(d2) * h;
  float nw = expf(d3) * w;
  oy1 = ncy - 0.5f * nh;
  ox1 = ncx - 0.5f * nw;
  oy2 = ncy + 0.5f * nh;
  ox2 = ncx + 0.5f * nw;
}

__device__ __forceinline__ float area_f(float4 bx) {
#pragma clang fp contract(off)
  return (bx.z - bx.x) * (bx.w - bx.y);
}

// EXACT equivalent of: fl32(inter/den) > 0.5 (RNE), den>0 — proof in R6/R7:
// collapses to (inter+inter) > den in plain f32.
__device__ __forceinline__ bool hit_f(float4 bi, float ia, float4 bj, float ja) {
#pragma clang fp contract(off)
  float yy1 = fmaxf(bi.x, bj.x);
  float xx1 = fmaxf(bi.y, bj.y);
  float yy2 = fminf(bi.z, bj.z);
  float xx2 = fminf(bi.w, bj.w);
  float ih = fmaxf(yy2 - yy1, 0.0f);
  float iw = fmaxf(xx2 - xx1, 0.0f);
  float inter = ih * iw;
  float den = ia + ja;
  den = den - inter;
  den = den + 1e-8f;
  return (inter + inter) > den;
}

// key packing: [63:32] score bits, [31:15] (131071-flat) so lower flat wins,
//              [14:5] n (payload only), [4:0] zero. Empty slot = 0.
__device__ __forceinline__ u64 pack_key(u32 sbits, int flat, int n) {
  return ((u64)sbits << 32) | ((u64)(131071 - flat) << 15) | ((u64)n << 5);
}

// --- kernel 1: background rows (argmax over classes == 0), wave per row ---
__global__ __launch_bounds__(256) void bg_kernel(const float* __restrict__ probs,
                                                 int* __restrict__ bg) {
  int row = blockIdx.x * 4 + (threadIdx.x >> 6);
  int lane = threadIdx.x & 63;
  if (row >= NB * NROI) return;
  const float* p = probs + (size_t)row * NCLS;
  float m = -1e30f;
  for (int idx = 1 + lane; idx < NCLS; idx += 64) m = fmaxf(m, p[idx]);
  for (int off = 32; off; off >>= 1) m = fmaxf(m, __shfl_xor(m, off));
  if (lane == 0) bg[row] = (p[0] >= m) ? 1 : 0;  // argmax==0 iff p0 >= all others
}

// --- kernel 2 (fused): gather + rank-sort + decode + intra-map/kept-sweep NMS ---
__global__ __launch_bounds__(NT) void gather_nms_kernel(
    const float* __restrict__ roi, const float* __restrict__ deltas,
    const float* __restrict__ probs, const int* __restrict__ bg,
    int* __restrict__ keep_count, u64* __restrict__ lane_key,
    int* __restrict__ bhist) {
  // XCD swizzle: 648 = 8*81; dispatch idx%8 = XCD -> XCD x owns batch x entirely
  int lane = (blockIdx.x % 8) * NCLS + blockIdx.x / 8;
  int b = lane / NCLS, c = lane % NCLS;
  int tid = threadIdx.x;
  int w = tid >> 6, l = tid & 63;

  // smem: [0,16K) sbox (alias: skeyU in [0,8K), dead after sort)
  //       [16K,24K) skey (sorted, live to the end)
  __shared__ alignas(16) char smem[24576];
  float4*     sbox   = (float4*)smem;
  u64*        skeyU  = (u64*)smem;
  ulonglong2* skeyU2 = (ulonglong2*)smem;
  u64*        skey   = (u64*)(smem + 16384);
  __shared__ u64 hmask_cur[64];
  __shared__ u64 keepmask[16];
  __shared__ u64 chunk_kept;
  __shared__ int scount, segbase[16];

  if (tid == 0) scount = 0;
  if (tid < 64) hmask_cur[tid] = 0ull;
  __syncthreads();

  // --- gather: score > 0.5 && !bg (ballot-aggregated append; M <= 1000) ---
  for (int base_n = 0; base_n < NROI; base_n += NT) {
    int n = base_n + tid;
    bool cand = false;
    float s = 0.0f;
    if (n < NROI) {
      int row = b * NROI + n;
      s = probs[(size_t)row * NCLS + c];
      cand = (s > SCORE_T) && (bg[row] == 0);
    }
    u64 bal = __ballot(cand);
    int wb = 0;
    if (l == 0) wb = atomicAdd(&scount, (int)__popcll(bal));
    wb = __shfl(wb, 0);
    if (cand) {
      int off = (int)__popcll(bal & ((1ull << l) - 1ull));
      skeyU[wb + off] = ((u64)__float_as_uint(s) << 32) | (u64)(0xFFFFFFFFu - (u32)n);
    }
  }
  __syncthreads();
  int M = scount;          // <= 1000
  if (tid == 0) skeyU[M] = 0ull;   // pad so the b128-packed q-loop is safe
  __syncthreads();
  int Mh = (M + 1) >> 1;

  // --- rank sort: keys unique -> rank is a permutation; b128 = 2 keys/read ---
  if (M <= NT) {           // block-uniform fast path: 1 key/thread
    u64 k0 = (tid < M) ? skeyU[tid] : 0ull;
    int r0 = 0;
    for (int q = 0; q < Mh; ++q) {   // broadcast reads, conflict-free
      ulonglong2 kq = skeyU2[q];
      r0 += (kq.x > k0);
      r0 += (kq.y > k0);
    }
    if (tid < 16) {
      int rem = M - (tid << 6);
      keepmask[tid] = (rem >= 64) ? ~0ull : ((rem <= 0) ? 0ull : ((1ull << rem) - 1ull));
    }
    if (tid < M) skey[r0] = k0;
  } else {                 // 2 keys/thread
    u64 k0 = skeyU[tid];
    u64 k1 = (tid + NT < M) ? skeyU[tid + NT] : 0ull;
    int r0 = 0, r1 = 0;
    for (int q = 0; q < Mh; ++q) {
      ulonglong2 kq = skeyU2[q];
      r0 += (kq.x > k0); r0 += (kq.y > k0);
      r1 += (kq.x > k1); r1 += (kq.y > k1);
    }
    if (tid < 16) {
      int rem = M - (tid << 6);
      keepmask[tid] = (rem >= 64) ? ~0ull : ((rem <= 0) ? 0ull : ((1ull << rem) - 1ull));
    }
    skey[r0] = k0;
    if (tid + NT < M) skey[r1] = k1;
  }
  __syncthreads();   // all skeyU reads done; skey ready

  // --- decode sorted candidates into sbox (overwrites dead skeyU region) ---
  for (int p = tid; p < M; p += NT) {
    u64 k = skey[p];
    u32 n = 0xFFFFFFFFu - (u32)(k & 0xFFFFFFFFull);
    int row = b * NROI + (int)n;
    float by1, bx1, by2, bx2;
    decode_box(roi + (size_t)row * 4, deltas + ((size_t)row * NCLS + c) * 4,
               by1, bx1, by2, bx2);
    sbox[p] = make_float4(by1, bx1, by2, bx2);
  }
  __syncthreads();   // decode done; sbox ready (chunk 0's intra-map reads it)

  // --- chunked greedy NMS: intra-chunk map + resolve + kept-only sweep ---
  int nchunks = (M + 63) >> 6;
  for (int ck = 0; ck < nchunks; ++ck) {
    int start = ck << 6;

    // intra map: wave w computes rows i = 8w..8w+7; lane l owns column l
    {
      float4 bL = sbox[start + l];     // coalesced; garbage beyond M masked later
      float aL = area_f(bL);
      u64 part = 0;
#pragma unroll
      for (int r = 0; r < 8; ++r) {
        int i = (w << 3) + r;
        float4 bi = sbox[start + i];   // broadcast
        float ia = area_f(bi);
        if (hit_f(bi, ia, bL, aL)) part |= (1ull << i);
      }
      if (part) atomicOr((unsigned long long*)&hmask_cur[l], (unsigned long long)part);
    }
    __syncthreads();   // B: hmask_cur complete; prev sweep's keepmask writes visible

    // resolve (wave 0): proven ballot greedy on the 64x64 matrix
    if (w == 0) {
      u64 kw = keepmask[ck];
      u64 row = hmask_cur[l];          // bit i = hit(box_i, box_l)
      hmask_cur[l] = 0ull;             // re-zero for next chunk (pre-C)
      bool alive = (kw >> l) & 1;
      u64 mask = alive ? (row & ((1ull << l) - 1ull)) : 0ull;
      u64 rem = ~__ballot(alive);
      for (int i = 0; i < 63; ++i) {
        if (!((rem >> i) & 1)) rem |= __ballot((mask >> i) & 1);  // uniform branch
      }
      bool kept = alive && !((rem >> l) & 1);
      u64 km = __ballot(kept);
      if (l == 0) { keepmask[ck] = km; chunk_kept = km; }
    }
    __syncthreads();   // C: km ready; hmask_cur zeroed

    // sweep: later j (lane-per-j) vs this chunk's ~10 kept boxes, inline
    u64 km = chunk_kept;
    for (int g = ck + 1 + w; g < nchunks; g += NW) {
      u64 kw = keepmask[g];            // this wave owns g this chunk
      if (kw == 0ull) continue;        // wave-uniform
      int j = (g << 6) + l;
      float4 bj = sbox[j];             // coalesced
      float ja = area_f(bj);
      bool hitany = false;
      u64 m2 = km;
      while (m2) {                     // wave-uniform loop over kept bits
        int i = __ffsll((unsigned long long)m2) - 1;
        m2 &= m2 - 1;
        float4 bi = sbox[start + i];   // broadcast
        float ia = area_f(bi);
        hitany |= hit_f(bi, ia, bj, ja);
      }
      bool supp = ((kw >> l) & 1) && hitany;
      u64 sb = __ballot(supp);
      if (l == 0 && sb) keepmask[g] = kw & ~sb;
    }
    // no barrier: next intra-map touches only hmask_cur (zeroed pre-C) and
    // read-only sbox; keepmask/chunk_kept access ordered by next B/C.
  }
  __syncthreads();

  // --- parallel compaction + fused per-batch 13-bit histogram ---
  if (tid < 16) {
    int acc = 0;
    for (int i = 0; i < tid; ++i) acc += (int)__popcll(keepmask[i]);
    segbase[tid] = acc;
  }
  __syncthreads();
  int total = segbase[15] + (int)__popcll(keepmask[15]);
  for (int s = 0; s < 2; ++s) {
    int seg = (w << 1) + s;
    u64 word = keepmask[seg];
    int p = (seg << 6) + l;
    if ((word >> l) & 1) {
      int rank = segbase[seg] + (int)__popcll(word & ((1ull << l) - 1ull));
      if (rank < MAXKEEP) {
        u64 k = skey[p];
        u32 sbits = (u32)(k >> 32);
        int n = (int)(0xFFFFFFFFu - (u32)(k & 0xFFFFFFFFull));
        lane_key[(size_t)lane * MAXKEEP + rank] = pack_key(sbits, c * NROI + p, n);
        atomicAdd(&bhist[b * HSIZE + (int)((sbits >> 10) & (HSIZE - 1))], 1);
      }
    }
  }
  if (tid == 0) keep_count[lane] = min(total, MAXKEEP);
}

// --- kernel 3: per-batch parallel top-200 (radix-select + bitonic), exact order ---
__global__ __launch_bounds__(512) void merge_kernel(
    const float* __restrict__ roi, const float* __restrict__ deltas,
    const int* __restrict__ keep_count, const u64* __restrict__ lane_key,
    const int* __restrict__ bhist,
    float* __restrict__ out_b, float* __restrict__ out_c, float* __restrict__ out_s) {
  int b = blockIdx.x;    // 8 blocks; idx%8 = XCD that produced batch b's keys
  int tid = threadIdx.x;

  __shared__ int hist[HSIZE];
  __shared__ int csum[256];
  __shared__ int cnts[NCLS];
  __shared__ int tb_sh, scnt_sh;
  __shared__ u64 surv[SCAP];

  for (int i = tid; i < HSIZE; i += 512) hist[i] = bhist[b * HSIZE + i];
  for (int i = tid; i < NCLS; i += 512) cnts[i] = keep_count[b * NCLS + i];
  if (tid == 0) { tb_sh = 0; scnt_sh = 0; }
  __syncthreads();

  // suffix sums; find tb = max bucket with sufsum >= 200 (0 if total < 200)
  int base = tid * 32;
  if (tid < 256) {
    int psum = 0;
    for (int i = 0; i < 32; ++i) psum += hist[base + i];
    csum[tid] = psum;
  }
  __syncthreads();
  if (tid == 0) {
    int acc = 0;
    for (int t = 255; t >= 0; --t) { acc += csum[t]; csum[t] = acc; }
  }
  __syncthreads();
  if (tid < 256) {
    int acc = (tid < 255) ? csum[tid + 1] : 0;
    int local_tb = -1;
    for (int i = 31; i >= 0; --i) {
      acc += hist[base + i];
      if (acc >= MAXKEEP && local_tb < 0) local_tb = base + i;
    }
    if (local_tb >= 0) atomicMax(&tb_sh, local_tb);
  }
  __syncthreads();
  int tb = tb_sh;

  // gather survivors (all keys in buckets >= tb; superset of exact top-200)
  for (int s = tid; s < NCLS * MAXKEEP; s += 512) {
    int c = s / MAXKEEP, h = s % MAXKEEP;
    if (h < cnts[c]) {
      u64 k = lane_key[((size_t)(b * NCLS + c)) * MAXKEEP + h];
      u32 sb = (u32)(k >> 32);
      if ((int)((sb >> 10) & (HSIZE - 1)) >= tb) {
        int pos = atomicAdd(&scnt_sh, 1);
        if (pos < SCAP) surv[pos] = k;
      }
    }
  }
  __syncthreads();
  int scnt = min(scnt_sh, SCAP);
  int size = 2;
  while (size < scnt) size <<= 1;
  for (int i = scnt + tid; i < size; i += 512) surv[i] = 0ull;
  __syncthreads();

  // bitonic sort descending by full key (score desc, flat asc)
  for (int k2 = 2; k2 <= size; k2 <<= 1) {
    for (int j = k2 >> 1; j > 0; j >>= 1) {
      for (int i = tid; i < size; i += 512) {
        int ixj = i ^ j;
        if (ixj > i) {
          u64 a = surv[i], bb = surv[ixj];
          bool swp = ((i & k2) == 0) ? (a < bb) : (a > bb);
          if (swp) { surv[i] = bb; surv[ixj] = a; }
        }
      }
      __syncthreads();
    }
  }

  // decode + write top-200 in parallel; zero-fill the rest
  for (int t = tid; t < MAXKEEP; t += 512) {
    size_t ob = ((size_t)b * MAXKEEP + t) * 4;
    if (t < scnt) {
      u64 k = surv[t];
      int flat = 131071 - (int)((k >> 15) & 0x1FFFF);
      int c = flat / NROI;
      int n = (int)((k >> 5) & 0x3FF);
      int row = b * NROI + n;
      float by1, bx1, by2, bx2;
      decode_box(roi + (size_t)row * 4, deltas + ((size_t)row * NCLS + c) * 4,
                 by1, bx1, by2, bx2);
      out_b[ob + 0] = fminf(fmaxf(by1, 0.0f), 1.0f);
      out_b[ob + 1] = fminf(fmaxf(bx1, 0.0f), 1.0f);
      out_b[ob + 2] = fminf(fmaxf(by2, 0.0f), 1.0f);
      out_b[ob + 3] = fminf(fmaxf(bx2, 0.0f), 1.0f);
      out_c[b * MAXKEEP + t] = (float)c;
      out_s[b * MAXKEEP + t] = __uint_as_float((u32)(k >> 32));
    } else {
      out_b[ob + 0] = 0.0f; out_b[ob + 1] = 0.0f;
      out_b[ob + 2] = 0.0f; out_b[ob + 3] = 0.0f;
      out_c[b * MAXKEEP + t] = 0.0f;
      out_s[b * MAXKEEP + t] = 0.0f;
    }
  }
}

extern "C" void kernel_launch(void* const* d_in, const int* in_sizes, int n_in,
                              void* d_out, int out_size, void* d_ws, size_t ws_size,
                              hipStream_t stream) {
  const float* roi    = (const float*)d_in[0];  // [8,1000,4]
  const float* deltas = (const float*)d_in[1];  // [8,1000,324]
  const float* probs  = (const float*)d_in[2];  // [8,1000,81]

  char* ws = (char*)d_ws;
  int* bg         = (int*)(ws);                   // 32000 B
  int* keep_count = (int*)(ws + 32768);           // 2592 B
  int* bhist      = (int*)(ws + 40960);           // 8*8192*4 = 262144 B
  u64* lane_key   = (u64*)(ws + 40960 + 262144);  // 648*200*8 = 1,036,800 B

  float* out_b = (float*)d_out;                 // [8,200,4]
  float* out_c = out_b + NB * MAXKEEP * 4;      // [8,200]
  float* out_s = out_c + NB * MAXKEEP;          // [8,200]

  hipMemsetAsync(bhist, 0, NB * HSIZE * sizeof(int), stream);
  bg_kernel<<<(NB * NROI + 3) / 4, 256, 0, stream>>>(probs, bg);
  gather_nms_kernel<<<NLANE, NT, 0, stream>>>(roi, deltas, probs, bg,
                                              keep_count, lane_key, bhist);
  merge_kernel<<<NB, 512, 0, stream>>>(roi, deltas, keep_count, lane_key, bhist,
                                       out_b, out_c, out_s);
}

// Round 12
// 136.916 us; speedup vs baseline: 1.4828x; 1.1676x over previous
//
#include <hip/hip_runtime.h>

#define NROI 1000
#define NCLS 81
#define NB   8
#define NLANE (NB*NCLS)        // 648 = 8 XCDs * 81
#define MAXM 1024
#define MAXKEEP 200
#define SCORE_T 0.5f
#define NT 512
#define NW 8                   // waves per block
#define HBITS 13
#define HSIZE (1<<HBITS)       // 8192 merge buckets
#define SCAP 1024

typedef unsigned long long u64;
typedef unsigned int u32;

// --- exact-order helpers (no FMA contraction; must match f32 numpy reference) ---

__device__ __forceinline__ void decode_box(const float* __restrict__ roi,
                                           const float* __restrict__ dl,
                                           float& oy1, float& ox1,
                                           float& oy2, float& ox2) {
#pragma clang fp contract(off)
  float y1 = roi[0], x1 = roi[1], y2 = roi[2], x2 = roi[3];
  float h = y2 - y1;
  float w = x2 - x1;
  float cy = y1 + 0.5f * h;
  float cx = x1 + 0.5f * w;
  float d0 = dl[0] * 0.1f;
  float d1 = dl[1] * 0.1f;
  float d2 = dl[2] * 0.2f;
  float d3 = dl[3] * 0.2f;
  float ncy = d0 * h + cy;
  float ncx = d1 * w + cx;
  float nh = expf(d2) * h;
  float nw = expf(d3) * w;
  oy1 = ncy - 0.5f * nh;
  ox1 = ncx - 0.5f * nw;
  oy2 = ncy + 0.5f * nh;
  ox2 = ncx + 0.5f * nw;
}

__device__ __forceinline__ float area_f(float4 bx) {
#pragma clang fp contract(off)
  return (bx.z - bx.x) * (bx.w - bx.y);
}

// EXACT equivalent of: fl32(inter/den) > 0.5 (RNE), den>0 — proof in R6/R7:
// collapses to (inter+inter) > den in plain f32.
__device__ __forceinline__ bool hit_f(float4 bi, float ia, float4 bj, float ja) {
#pragma clang fp contract(off)
  float yy1 = fmaxf(bi.x, bj.x);
  float xx1 = fmaxf(bi.y, bj.y);
  float yy2 = fminf(bi.z, bj.z);
  float xx2 = fminf(bi.w, bj.w);
  float ih = fmaxf(yy2 - yy1, 0.0f);
  float iw = fmaxf(xx2 - xx1, 0.0f);
  float inter = ih * iw;
  float den = ia + ja;
  den = den - inter;
  den = den + 1e-8f;
  return (inter + inter) > den;
}

// key packing: [63:32] score bits, [31:15] (131071-flat) so lower flat wins,
//              [14:5] n (payload only), [4:0] zero. Empty slot = 0.
__device__ __forceinline__ u64 pack_key(u32 sbits, int flat, int n) {
  return ((u64)sbits << 32) | ((u64)(131071 - flat) << 15) | ((u64)n << 5);
}

// --- kernel 1: background rows (argmax over classes == 0), wave per row ---
__global__ __launch_bounds__(256) void bg_kernel(const float* __restrict__ probs,
                                                 int* __restrict__ bg) {
  int row = blockIdx.x * 4 + (threadIdx.x >> 6);
  int lane = threadIdx.x & 63;
  if (row >= NB * NROI) return;
  const float* p = probs + (size_t)row * NCLS;
  float m = -1e30f;
  for (int idx = 1 + lane; idx < NCLS; idx += 64) m = fmaxf(m, p[idx]);
  for (int off = 32; off; off >>= 1) m = fmaxf(m, __shfl_xor(m, off));
  if (lane == 0) bg[row] = (p[0] >= m) ? 1 : 0;  // argmax==0 iff p0 >= all others
}

// --- kernel 2 (fused): gather + counting-sort + decode + intra-map/sweep NMS ---
__global__ __launch_bounds__(NT) void gather_nms_kernel(
    const float* __restrict__ roi, const float* __restrict__ deltas,
    const float* __restrict__ probs, const int* __restrict__ bg,
    int* __restrict__ keep_count, u64* __restrict__ lane_key,
    int* __restrict__ bhist) {
  // XCD swizzle: 648 = 8*81; dispatch idx%8 = XCD -> XCD x owns batch x entirely
  int lane = (blockIdx.x % 8) * NCLS + blockIdx.x / 8;
  int b = lane / NCLS, c = lane % NCLS;
  int tid = threadIdx.x;
  int w = tid >> 6, l = tid & 63;

  // smem: [0,16K) sbox; aliases skeyU [0,8K) (gather order) and
  //       skeyB [8K,16K) (bucket-scattered) — both dead before decode.
  //       [16K,24K) skey (final sorted, live to the end)
  //       [24K,25K) bcnt[256] (cursor/end); [25K,26K) bstart[256]
  __shared__ alignas(16) char smem[26624];
  float4* sbox   = (float4*)smem;
  u64*    skeyU  = (u64*)smem;
  u64*    skeyB  = (u64*)(smem + 8192);
  u64*    skey   = (u64*)(smem + 16384);
  int*    bcnt   = (int*)(smem + 24576);
  int*    bstart = (int*)(smem + 25600);
  __shared__ u64 hmask_cur[64];
  __shared__ u64 keepmask[16];
  __shared__ u64 chunk_kept;
  __shared__ int scount, segbase[16];

  if (tid == 0) scount = 0;
  if (tid < 64) hmask_cur[tid] = 0ull;
  if (tid < 256) bcnt[tid] = 0;
  __syncthreads();

  // --- gather: score > 0.5 && !bg, + 8-bit score histogram (fused) ---
  for (int base_n = 0; base_n < NROI; base_n += NT) {
    int n = base_n + tid;
    bool cand = false;
    float s = 0.0f;
    if (n < NROI) {
      int row = b * NROI + n;
      s = probs[(size_t)row * NCLS + c];
      cand = (s > SCORE_T) && (bg[row] == 0);
    }
    u64 bal = __ballot(cand);
    int wb = 0;
    if (l == 0) wb = atomicAdd(&scount, (int)__popcll(bal));
    wb = __shfl(wb, 0);
    if (cand) {
      int off = (int)__popcll(bal & ((1ull << l) - 1ull));
      u32 sb = __float_as_uint(s);
      skeyU[wb + off] = ((u64)sb << 32) | (u64)(0xFFFFFFFFu - (u32)n);
      // scores in (0.5,1): exponent fixed -> top-8 mantissa bits are monotone
      atomicAdd(&bcnt[(sb >> 15) & 255], 1);
    }
  }
  __syncthreads();
  int M = scount;          // <= 1000

  // --- descending bucket scan (wave 0): bstart/bcnt = start cursors ---
  if (w == 0) {
    int d0 = 4 * l, d1 = d0 + 1, d2 = d0 + 2, d3 = d0 + 3;  // descending order idx
    int c0 = bcnt[255 - d0], c1 = bcnt[255 - d1];
    int c2 = bcnt[255 - d2], c3 = bcnt[255 - d3];
    int t = c0 + c1 + c2 + c3;
    int inc = t;
    for (int off = 1; off < 64; off <<= 1) {
      int v = __shfl_up(inc, off);
      if (l >= off) inc += v;
    }
    int excl = inc - t;      // keys in strictly higher-score buckets
    int s0 = excl, s1 = excl + c0, s2 = excl + c0 + c1, s3 = excl + c0 + c1 + c2;
    bcnt[255 - d0] = s0; bstart[255 - d0] = s0;
    bcnt[255 - d1] = s1; bstart[255 - d1] = s1;
    bcnt[255 - d2] = s2; bstart[255 - d2] = s2;
    bcnt[255 - d3] = s3; bstart[255 - d3] = s3;
  }
  __syncthreads();

  // --- scatter into bucket runs (arrival order within run) ---
  for (int p = tid; p < M; p += NT) {
    u64 k = skeyU[p];
    int bkt = (int)((k >> 47) & 255);        // == (sbits>>15)&255
    int pos = atomicAdd(&bcnt[bkt], 1);
    skeyB[pos] = k;
  }
  __syncthreads();

  // --- exact cleanup: global rank = bucket start + #greater in run (~2 keys) ---
  for (int p = tid; p < M; p += NT) {
    u64 k = skeyB[p];
    int bkt = (int)((k >> 47) & 255);
    int st = bstart[bkt], en = bcnt[bkt];    // bcnt is now the run end
    int r = st;
    for (int q = st; q < en; ++q) r += (skeyB[q] > k) ? 1 : 0;  // keys unique
    skey[r] = k;
  }
  if (tid < 16) {            // keep bitmask init: bits p < M set
    int rem = M - (tid << 6);
    keepmask[tid] = (rem >= 64) ? ~0ull : ((rem <= 0) ? 0ull : ((1ull << rem) - 1ull));
  }
  __syncthreads();   // skey (sorted) ready; skeyU/skeyB dead

  // --- decode sorted candidates into sbox (overwrites dead skeyU/skeyB) ---
  for (int p = tid; p < M; p += NT) {
    u64 k = skey[p];
    u32 n = 0xFFFFFFFFu - (u32)(k & 0xFFFFFFFFull);
    int row = b * NROI + (int)n;
    float by1, bx1, by2, bx2;
    decode_box(roi + (size_t)row * 4, deltas + ((size_t)row * NCLS + c) * 4,
               by1, bx1, by2, bx2);
    sbox[p] = make_float4(by1, bx1, by2, bx2);
  }
  __syncthreads();   // decode done; sbox ready (chunk 0's intra-map reads it)

  // --- chunked greedy NMS: intra-chunk map + resolve + kept-only sweep ---
  int nchunks = (M + 63) >> 6;
  for (int ck = 0; ck < nchunks; ++ck) {
    int start = ck << 6;

    // intra map: wave w computes rows i = 8w..8w+7; lane l owns column l
    {
      float4 bL = sbox[start + l];     // coalesced; garbage beyond M masked later
      float aL = area_f(bL);
      u64 part = 0;
#pragma unroll
      for (int r = 0; r < 8; ++r) {
        int i = (w << 3) + r;
        float4 bi = sbox[start + i];   // broadcast
        float ia = area_f(bi);
        if (hit_f(bi, ia, bL, aL)) part |= (1ull << i);
      }
      if (part) atomicOr((unsigned long long*)&hmask_cur[l], (unsigned long long)part);
    }
    __syncthreads();   // B: hmask_cur complete; prev sweep's keepmask writes visible

    // resolve (wave 0): proven ballot greedy on the 64x64 matrix
    if (w == 0) {
      u64 kw = keepmask[ck];
      u64 row = hmask_cur[l];          // bit i = hit(box_i, box_l)
      hmask_cur[l] = 0ull;             // re-zero for next chunk (pre-C)
      bool alive = (kw >> l) & 1;
      u64 mask = alive ? (row & ((1ull << l) - 1ull)) : 0ull;
      u64 rem = ~__ballot(alive);
      for (int i = 0; i < 63; ++i) {
        if (!((rem >> i) & 1)) rem |= __ballot((mask >> i) & 1);  // uniform branch
      }
      bool kept = alive && !((rem >> l) & 1);
      u64 km = __ballot(kept);
      if (l == 0) { keepmask[ck] = km; chunk_kept = km; }
    }
    __syncthreads();   // C: km ready; hmask_cur zeroed

    // sweep: later j (lane-per-j) vs this chunk's ~10 kept boxes, inline
    u64 km = chunk_kept;
    for (int g = ck + 1 + w; g < nchunks; g += NW) {
      u64 kw = keepmask[g];            // this wave owns g this chunk
      if (kw == 0ull) continue;        // wave-uniform
      int j = (g << 6) + l;
      float4 bj = sbox[j];             // coalesced
      float ja = area_f(bj);
      bool hitany = false;
      u64 m2 = km;
      while (m2) {                     // wave-uniform loop over kept bits
        int i = __ffsll((unsigned long long)m2) - 1;
        m2 &= m2 - 1;
        float4 bi = sbox[start + i];   // broadcast
        float ia = area_f(bi);
        hitany |= hit_f(bi, ia, bj, ja);
      }
      bool supp = ((kw >> l) & 1) && hitany;
      u64 sb = __ballot(supp);
      if (l == 0 && sb) keepmask[g] = kw & ~sb;
    }
    // no barrier: next intra-map touches only hmask_cur (zeroed pre-C) and
    // read-only sbox; keepmask/chunk_kept access ordered by next B/C.
  }
  __syncthreads();

  // --- parallel compaction + fused per-batch 13-bit histogram ---
  if (tid < 16) {
    int acc = 0;
    for (int i = 0; i < tid; ++i) acc += (int)__popcll(keepmask[i]);
    segbase[tid] = acc;
  }
  __syncthreads();
  int total = segbase[15] + (int)__popcll(keepmask[15]);
  for (int s = 0; s < 2; ++s) {
    int seg = (w << 1) + s;
    u64 word = keepmask[seg];
    int p = (seg << 6) + l;
    if ((word >> l) & 1) {
      int rank = segbase[seg] + (int)__popcll(word & ((1ull << l) - 1ull));
      if (rank < MAXKEEP) {
        u64 k = skey[p];
        u32 sbits = (u32)(k >> 32);
        int n = (int)(0xFFFFFFFFu - (u32)(k & 0xFFFFFFFFull));
        lane_key[(size_t)lane * MAXKEEP + rank] = pack_key(sbits, c * NROI + p, n);
        atomicAdd(&bhist[b * HSIZE + (int)((sbits >> 10) & (HSIZE - 1))], 1);
      }
    }
  }
  if (tid == 0) keep_count[lane] = min(total, MAXKEEP);
}

// --- kernel 3: per-batch parallel top-200 (radix-select + bitonic), exact order ---
__global__ __launch_bounds__(512) void merge_kernel(
    const float* __restrict__ roi, const float* __restrict__ deltas,
    const int* __restrict__ keep_count, const u64* __restrict__ lane_key,
    const int* __restrict__ bhist,
    float* __restrict__ out_b, float* __restrict__ out_c, float* __restrict__ out_s) {
  int b = blockIdx.x;    // 8 blocks; idx%8 = XCD that produced batch b's keys
  int tid = threadIdx.x;

  __shared__ int hist[HSIZE];
  __shared__ int csum[256];
  __shared__ int cnts[NCLS];
  __shared__ int tb_sh, scnt_sh;
  __shared__ u64 surv[SCAP];

  for (int i = tid; i < HSIZE; i += 512) hist[i] = bhist[b * HSIZE + i];
  for (int i = tid; i < NCLS; i += 512) cnts[i] = keep_count[b * NCLS + i];
  if (tid == 0) { tb_sh = 0; scnt_sh = 0; }
  __syncthreads();

  // suffix sums; find tb = max bucket with sufsum >= 200 (0 if total < 200)
  int base = tid * 32;
  if (tid < 256) {
    int psum = 0;
    for (int i = 0; i < 32; ++i) psum += hist[base + i];
    csum[tid] = psum;
  }
  __syncthreads();
  if (tid == 0) {
    int acc = 0;
    for (int t = 255; t >= 0; --t) { acc += csum[t]; csum[t] = acc; }
  }
  __syncthreads();
  if (tid < 256) {
    int acc = (tid < 255) ? csum[tid + 1] : 0;
    int local_tb = -1;
    for (int i = 31; i >= 0; --i) {
      acc += hist[base + i];
      if (acc >= MAXKEEP && local_tb < 0) local_tb = base + i;
    }
    if (local_tb >= 0) atomicMax(&tb_sh, local_tb);
  }
  __syncthreads();
  int tb = tb_sh;

  // gather survivors (all keys in buckets >= tb; superset of exact top-200)
  for (int s = tid; s < NCLS * MAXKEEP; s += 512) {
    int c = s / MAXKEEP, h = s % MAXKEEP;
    if (h < cnts[c]) {
      u64 k = lane_key[((size_t)(b * NCLS + c)) * MAXKEEP + h];
      u32 sb = (u32)(k >> 32);
      if ((int)((sb >> 10) & (HSIZE - 1)) >= tb) {
        int pos = atomicAdd(&scnt_sh, 1);
        if (pos < SCAP) surv[pos] = k;
      }
    }
  }
  __syncthreads();
  int scnt = min(scnt_sh, SCAP);
  int size = 2;
  while (size < scnt) size <<= 1;
  for (int i = scnt + tid; i < size; i += 512) surv[i] = 0ull;
  __syncthreads();

  // bitonic sort descending by full key (score desc, flat asc)
  for (int k2 = 2; k2 <= size; k2 <<= 1) {
    for (int j = k2 >> 1; j > 0; j >>= 1) {
      for (int i = tid; i < size; i += 512) {
        int ixj = i ^ j;
        if (ixj > i) {
          u64 a = surv[i], bb = surv[ixj];
          bool swp = ((i & k2) == 0) ? (a < bb) : (a > bb);
          if (swp) { surv[i] = bb; surv[ixj] = a; }
        }
      }
      __syncthreads();
    }
  }

  // decode + write top-200 in parallel; zero-fill the rest
  for (int t = tid; t < MAXKEEP; t += 512) {
    size_t ob = ((size_t)b * MAXKEEP + t) * 4;
    if (t < scnt) {
      u64 k = surv[t];
      int flat = 131071 - (int)((k >> 15) & 0x1FFFF);
      int c = flat / NROI;
      int n = (int)((k >> 5) & 0x3FF);
      int row = b * NROI + n;
      float by1, bx1, by2, bx2;
      decode_box(roi + (size_t)row * 4, deltas + ((size_t)row * NCLS + c) * 4,
                 by1, bx1, by2, bx2);
      out_b[ob + 0] = fminf(fmaxf(by1, 0.0f), 1.0f);
      out_b[ob + 1] = fminf(fmaxf(bx1, 0.0f), 1.0f);
      out_b[ob + 2] = fminf(fmaxf(by2, 0.0f), 1.0f);
      out_b[ob + 3] = fminf(fmaxf(bx2, 0.0f), 1.0f);
      out_c[b * MAXKEEP + t] = (float)c;
      out_s[b * MAXKEEP + t] = __uint_as_float((u32)(k >> 32));
    } else {
      out_b[ob + 0] = 0.0f; out_b[ob + 1] = 0.0f;
      out_b[ob + 2] = 0.0f; out_b[ob + 3] = 0.0f;
      out_c[b * MAXKEEP + t] = 0.0f;
      out_s[b * MAXKEEP + t] = 0.0f;
    }
  }
}

extern "C" void kernel_launch(void* const* d_in, const int* in_sizes, int n_in,
                              void* d_out, int out_size, void* d_ws, size_t ws_size,
                              hipStream_t stream) {
  const float* roi    = (const float*)d_in[0];  // [8,1000,4]
  const float* deltas = (const float*)d_in[1];  // [8,1000,324]
  const float* probs  = (const float*)d_in[2];  // [8,1000,81]

  char* ws = (char*)d_ws;
  int* bg         = (int*)(ws);                   // 32000 B
  int* keep_count = (int*)(ws + 32768);           // 2592 B
  int* bhist      = (int*)(ws + 40960);           // 8*8192*4 = 262144 B
  u64* lane_key   = (u64*)(ws + 40960 + 262144);  // 648*200*8 = 1,036,800 B

  float* out_b = (float*)d_out;                 // [8,200,4]
  float* out_c = out_b + NB * MAXKEEP * 4;      // [8,200]
  float* out_s = out_c + NB * MAXKEEP;          // [8,200]

  hipMemsetAsync(bhist, 0, NB * HSIZE * sizeof(int), stream);
  bg_kernel<<<(NB * NROI + 3) / 4, 256, 0, stream>>>(probs, bg);
  gather_nms_kernel<<<NLANE, NT, 0, stream>>>(roi, deltas, probs, bg,
                                              keep_count, lane_key, bhist);
  merge_kernel<<<NB, 512, 0, stream>>>(roi, deltas, keep_count, lane_key, bhist,
                                       out_b, out_c, out_s);
}

// Round 13
// 97.309 us; speedup vs baseline: 2.0863x; 1.4070x over previous
//
#include <hip/hip_runtime.h>

#define NROI 1000
#define NCLS 81
#define NB   8
#define NLANE (NB*NCLS)        // 648 = 8 XCDs * 81
#define MAXM 1024
#define MAXKEEP 200
#define SCORE_T 0.5f
#define NT 512
#define NW 8                   // waves per block
#define HBITS 13
#define HSIZE (1<<HBITS)       // 8192 merge buckets
#define SCAP 1024

typedef unsigned long long u64;
typedef unsigned int u32;

// --- exact-order helpers (no FMA contraction; must match f32 numpy reference) ---

__device__ __forceinline__ void decode_box(const float* __restrict__ roi,
                                           const float* __restrict__ dl,
                                           float& oy1, float& ox1,
                                           float& oy2, float& ox2) {
#pragma clang fp contract(off)
  float y1 = roi[0], x1 = roi[1], y2 = roi[2], x2 = roi[3];
  float h = y2 - y1;
  float w = x2 - x1;
  float cy = y1 + 0.5f * h;
  float cx = x1 + 0.5f * w;
  float d0 = dl[0] * 0.1f;
  float d1 = dl[1] * 0.1f;
  float d2 = dl[2] * 0.2f;
  float d3 = dl[3] * 0.2f;
  float ncy = d0 * h + cy;
  float ncx = d1 * w + cx;
  float nh = expf(d2) * h;
  float nw = expf(d3) * w;
  oy1 = ncy - 0.5f * nh;
  ox1 = ncx - 0.5f * nw;
  oy2 = ncy + 0.5f * nh;
  ox2 = ncx + 0.5f * nw;
}

__device__ __forceinline__ float area_f(float4 bx) {
#pragma clang fp contract(off)
  return (bx.z - bx.x) * (bx.w - bx.y);
}

// EXACT equivalent of: fl32(inter/den) > 0.5 (RNE), den>0 — proof in R6/R7:
// collapses to (inter+inter) > den in plain f32.
__device__ __forceinline__ bool hit_f(float4 bi, float ia, float4 bj, float ja) {
#pragma clang fp contract(off)
  float yy1 = fmaxf(bi.x, bj.x);
  float xx1 = fmaxf(bi.y, bj.y);
  float yy2 = fminf(bi.z, bj.z);
  float xx2 = fminf(bi.w, bj.w);
  float ih = fmaxf(yy2 - yy1, 0.0f);
  float iw = fmaxf(xx2 - xx1, 0.0f);
  float inter = ih * iw;
  float den = ia + ja;
  den = den - inter;
  den = den + 1e-8f;
  return (inter + inter) > den;
}

// key packing: [63:32] score bits, [31:15] (131071-flat) so lower flat wins,
//              [14:5] n (payload only), [4:0] zero. Empty slot = 0.
__device__ __forceinline__ u64 pack_key(u32 sbits, int flat, int n) {
  return ((u64)sbits << 32) | ((u64)(131071 - flat) << 15) | ((u64)n << 5);
}

// --- kernel 1: background rows (argmax over classes == 0), wave per row ---
__global__ __launch_bounds__(256) void bg_kernel(const float* __restrict__ probs,
                                                 int* __restrict__ bg) {
  int row = blockIdx.x * 4 + (threadIdx.x >> 6);
  int lane = threadIdx.x & 63;
  if (row >= NB * NROI) return;
  const float* p = probs + (size_t)row * NCLS;
  float m = -1e30f;
  for (int idx = 1 + lane; idx < NCLS; idx += 64) m = fmaxf(m, p[idx]);
  for (int off = 32; off; off >>= 1) m = fmaxf(m, __shfl_xor(m, off));
  if (lane == 0) bg[row] = (p[0] >= m) ? 1 : 0;  // argmax==0 iff p0 >= all others
}

// --- kernel 2 (fused): gather + counting sort + lazy-decode NMS w/ early stop ---
__global__ __launch_bounds__(NT) void gather_nms_kernel(
    const float* __restrict__ roi, const float* __restrict__ deltas,
    const float* __restrict__ probs, const int* __restrict__ bg,
    int* __restrict__ keep_count, u64* __restrict__ lane_key,
    int* __restrict__ bhist) {
  // XCD swizzle: 648 = 8*81; dispatch idx%8 = XCD -> XCD x owns batch x entirely
  int lane = (blockIdx.x % 8) * NCLS + blockIdx.x / 8;
  int b = lane / NCLS, c = lane % NCLS;
  int tid = threadIdx.x;
  int w = tid >> 6, l = tid & 63;

  // smem: [0,16K) sbox; aliases skeyU [0,8K) + skeyB [8K,16K) (dead pre-decode)
  //       [16K,24K) skey (final sorted, live to the end)
  //       [24K,25K) bcnt[256]; [25K,26K) bstart[256]
  __shared__ alignas(16) char smem[26624];
  float4* sbox   = (float4*)smem;
  u64*    skeyU  = (u64*)smem;
  u64*    skeyB  = (u64*)(smem + 8192);
  u64*    skey   = (u64*)(smem + 16384);
  int*    bcnt   = (int*)(smem + 24576);
  int*    bstart = (int*)(smem + 25600);
  __shared__ u64 hmask_cur[64];
  __shared__ u64 keepmask[16];
  __shared__ int scount, segbase[16], kc_sh;

  if (tid == 0) { scount = 0; kc_sh = 0; }
  if (tid < 64) hmask_cur[tid] = 0ull;
  if (tid < 256) bcnt[tid] = 0;
  __syncthreads();

  // --- gather: score > 0.5 && !bg, + 8-bit score histogram (fused) ---
  for (int base_n = 0; base_n < NROI; base_n += NT) {
    int n = base_n + tid;
    bool cand = false;
    float s = 0.0f;
    if (n < NROI) {
      int row = b * NROI + n;
      s = probs[(size_t)row * NCLS + c];
      cand = (s > SCORE_T) && (bg[row] == 0);
    }
    u64 bal = __ballot(cand);
    int wb = 0;
    if (l == 0) wb = atomicAdd(&scount, (int)__popcll(bal));
    wb = __shfl(wb, 0);
    if (cand) {
      int off = (int)__popcll(bal & ((1ull << l) - 1ull));
      u32 sb = __float_as_uint(s);
      skeyU[wb + off] = ((u64)sb << 32) | (u64)(0xFFFFFFFFu - (u32)n);
      // scores in (0.5,1): exponent fixed -> top-8 mantissa bits are monotone
      atomicAdd(&bcnt[(sb >> 15) & 255], 1);
    }
  }
  __syncthreads();
  int M = scount;          // <= 1000

  // --- descending bucket scan (wave 0): bstart/bcnt = start cursors ---
  if (w == 0) {
    int d0 = 4 * l, d1 = d0 + 1, d2 = d0 + 2, d3 = d0 + 3;
    int c0 = bcnt[255 - d0], c1 = bcnt[255 - d1];
    int c2 = bcnt[255 - d2], c3 = bcnt[255 - d3];
    int t = c0 + c1 + c2 + c3;
    int inc = t;
    for (int off = 1; off < 64; off <<= 1) {
      int v = __shfl_up(inc, off);
      if (l >= off) inc += v;
    }
    int excl = inc - t;
    int s0 = excl, s1 = excl + c0, s2 = excl + c0 + c1, s3 = excl + c0 + c1 + c2;
    bcnt[255 - d0] = s0; bstart[255 - d0] = s0;
    bcnt[255 - d1] = s1; bstart[255 - d1] = s1;
    bcnt[255 - d2] = s2; bstart[255 - d2] = s2;
    bcnt[255 - d3] = s3; bstart[255 - d3] = s3;
  }
  __syncthreads();

  // --- scatter into bucket runs (arrival order within run) ---
  for (int p = tid; p < M; p += NT) {
    u64 k = skeyU[p];
    int bkt = (int)((k >> 47) & 255);
    int pos = atomicAdd(&bcnt[bkt], 1);
    skeyB[pos] = k;
  }
  __syncthreads();

  // --- exact cleanup: global rank = bucket start + #greater in run ---
  for (int p = tid; p < M; p += NT) {
    u64 k = skeyB[p];
    int bkt = (int)((k >> 47) & 255);
    int st = bstart[bkt], en = bcnt[bkt];
    int r = st;
    for (int q = st; q < en; ++q) r += (skeyB[q] > k) ? 1 : 0;  // keys unique
    skey[r] = k;
  }
  if (tid < 16) {            // keep bitmask init: bits p < M set
    int rem = M - (tid << 6);
    keepmask[tid] = (rem >= 64) ? ~0ull : ((rem <= 0) ? 0ull : ((1ull << rem) - 1ull));
  }
  __syncthreads();   // skey sorted; skeyU/skeyB dead -> sbox region free

  // --- chunked greedy NMS: lazy decode + lazy suppress + early termination ---
  int nchunks = (M + 63) >> 6;
  for (int ck = 0; ck < nchunks; ++ck) {
    int start = ck << 6;
    int p = start + l;

    // (a) decode own chunk box into regs + sbox (garbage beyond M: clamped row)
    u64 kown = skey[p];                      // p < 1024 always
    int nn = (int)(0xFFFFFFFFu - (u32)(kown & 0xFFFFFFFFull));
    int row = b * NROI + ((p < M) ? nn : 0); // clamp: no OOB global reads
    float4 bj;
    {
      float by1, bx1, by2, bx2;
      decode_box(roi + (size_t)row * 4, deltas + ((size_t)row * NCLS + c) * 4,
                 by1, bx1, by2, bx2);
      bj = make_float4(by1, bx1, by2, bx2);
    }
    float ja = area_f(bj);
    sbox[p] = bj;
    __syncthreads();   // A: this chunk's sbox visible; prev km visible

    // (d1) intra map: wave w computes rows i = 8w..8w+7 vs own box (column l)
    {
      u64 part = 0;
#pragma unroll
      for (int r = 0; r < 8; ++r) {
        int i = (w << 3) + r;
        float4 bi = sbox[start + i];         // broadcast
        float ia = area_f(bi);
        if (hit_f(bi, ia, bj, ja)) part |= (1ull << i);
      }
      if (part) atomicOr((unsigned long long*)&hmask_cur[l], (unsigned long long)part);
    }
    // (d2) lazy suppress: own box vs kept boxes of previous chunks (wave-split)
    {
      bool supp = false;
      for (int q = w; q < ck; q += NW) {
        u64 mq = keepmask[q];                // final km of chunk q
        while (mq) {                         // wave-uniform
          int i = __ffsll((unsigned long long)mq) - 1;
          mq &= mq - 1;
          float4 bi = sbox[(q << 6) + i];    // broadcast
          float ia = area_f(bi);
          supp |= hit_f(bi, ia, bj, ja);
        }
      }
      u64 sb = __ballot(supp);
      if (l == 0 && sb) {                    // 32-bit halves: bitwise AND is safe
        u32* km32 = (u32*)&keepmask[ck];
        u32 lo = (u32)(sb & 0xFFFFFFFFull), hi = (u32)(sb >> 32);
        if (lo) atomicAnd(&km32[0], ~lo);
        if (hi) atomicAnd(&km32[1], ~hi);
      }
    }
    __syncthreads();   // B: keepmask[ck] final, hmask_cur complete

    // (f) resolve (wave 0): ffs loop, iterations = #kept in chunk
    if (w == 0) {
      u64 rowm = hmask_cur[l];               // bit i = hit(box_i, box_l)
      hmask_cur[l] = 0ull;                   // re-zero for next chunk
      u64 rem = keepmask[ck];
      u64 kept = 0;
      while (rem) {                          // wave-uniform
        int i = __ffsll((unsigned long long)rem) - 1;
        kept |= (1ull << i);
        rem &= ~(1ull << i);
        bool s = (l > i) && ((rowm >> i) & 1);
        u64 sb2 = __ballot(s);
        rem &= ~sb2;
      }
      if (l == 0) { keepmask[ck] = kept; kc_sh += (int)__popcll(kept); }
    }
    __syncthreads();   // C: km + kc_sh ready; hmask_cur zeroed

    // early termination: first 200 kept fully determined (cumsum cap)
    if (kc_sh >= MAXKEEP) break;             // block-uniform
    // stale keepmask words beyond the break have rank >= kc_sh >= 200 ->
    // filtered by rank < MAXKEEP below; min(total,200) stays exact.
  }
  __syncthreads();

  // --- parallel compaction + fused per-batch 13-bit histogram ---
  if (tid < 16) {
    int acc = 0;
    for (int i = 0; i < tid; ++i) acc += (int)__popcll(keepmask[i]);
    segbase[tid] = acc;
  }
  __syncthreads();
  int total = segbase[15] + (int)__popcll(keepmask[15]);
  for (int s = 0; s < 2; ++s) {
    int seg = (w << 1) + s;
    u64 word = keepmask[seg];
    int p = (seg << 6) + l;
    if ((word >> l) & 1) {
      int rank = segbase[seg] + (int)__popcll(word & ((1ull << l) - 1ull));
      if (rank < MAXKEEP) {
        u64 k = skey[p];
        u32 sbits = (u32)(k >> 32);
        int n = (int)(0xFFFFFFFFu - (u32)(k & 0xFFFFFFFFull));
        lane_key[(size_t)lane * MAXKEEP + rank] = pack_key(sbits, c * NROI + p, n);
        atomicAdd(&bhist[b * HSIZE + (int)((sbits >> 10) & (HSIZE - 1))], 1);
      }
    }
  }
  if (tid == 0) keep_count[lane] = min(total, MAXKEEP);
}

// --- kernel 3: per-batch parallel top-200 (radix-select + bitonic), exact order ---
__global__ __launch_bounds__(512) void merge_kernel(
    const float* __restrict__ roi, const float* __restrict__ deltas,
    const int* __restrict__ keep_count, const u64* __restrict__ lane_key,
    const int* __restrict__ bhist,
    float* __restrict__ out_b, float* __restrict__ out_c, float* __restrict__ out_s) {
  int b = blockIdx.x;    // 8 blocks; idx%8 = XCD that produced batch b's keys
  int tid = threadIdx.x;

  __shared__ int hist[HSIZE];
  __shared__ int csum[256];
  __shared__ int cnts[NCLS];
  __shared__ int tb_sh, scnt_sh;
  __shared__ u64 surv[SCAP];

  for (int i = tid; i < HSIZE; i += 512) hist[i] = bhist[b * HSIZE + i];
  for (int i = tid; i < NCLS; i += 512) cnts[i] = keep_count[b * NCLS + i];
  if (tid == 0) { tb_sh = 0; scnt_sh = 0; }
  __syncthreads();

  // suffix sums; find tb = max bucket with sufsum >= 200 (0 if total < 200)
  int base = tid * 32;
  if (tid < 256) {
    int psum = 0;
    for (int i = 0; i < 32; ++i) psum += hist[base + i];
    csum[tid] = psum;
  }
  __syncthreads();
  if (tid == 0) {
    int acc = 0;
    for (int t = 255; t >= 0; --t) { acc += csum[t]; csum[t] = acc; }
  }
  __syncthreads();
  if (tid < 256) {
    int acc = (tid < 255) ? csum[tid + 1] : 0;
    int local_tb = -1;
    for (int i = 31; i >= 0; --i) {
      acc += hist[base + i];
      if (acc >= MAXKEEP && local_tb < 0) local_tb = base + i;
    }
    if (local_tb >= 0) atomicMax(&tb_sh, local_tb);
  }
  __syncthreads();
  int tb = tb_sh;

  // gather survivors (all keys in buckets >= tb; superset of exact top-200)
  for (int s = tid; s < NCLS * MAXKEEP; s += 512) {
    int c = s / MAXKEEP, h = s % MAXKEEP;
    if (h < cnts[c]) {
      u64 k = lane_key[((size_t)(b * NCLS + c)) * MAXKEEP + h];
      u32 sb = (u32)(k >> 32);
      if ((int)((sb >> 10) & (HSIZE - 1)) >= tb) {
        int pos = atomicAdd(&scnt_sh, 1);
        if (pos < SCAP) surv[pos] = k;
      }
    }
  }
  __syncthreads();
  int scnt = min(scnt_sh, SCAP);
  int size = 2;
  while (size < scnt) size <<= 1;
  for (int i = scnt + tid; i < size; i += 512) surv[i] = 0ull;
  __syncthreads();

  // bitonic sort descending by full key (score desc, flat asc)
  for (int k2 = 2; k2 <= size; k2 <<= 1) {
    for (int j = k2 >> 1; j > 0; j >>= 1) {
      for (int i = tid; i < size; i += 512) {
        int ixj = i ^ j;
        if (ixj > i) {
          u64 a = surv[i], bb = surv[ixj];
          bool swp = ((i & k2) == 0) ? (a < bb) : (a > bb);
          if (swp) { surv[i] = bb; surv[ixj] = a; }
        }
      }
      __syncthreads();
    }
  }

  // decode + write top-200 in parallel; zero-fill the rest
  for (int t = tid; t < MAXKEEP; t += 512) {
    size_t ob = ((size_t)b * MAXKEEP + t) * 4;
    if (t < scnt) {
      u64 k = surv[t];
      int flat = 131071 - (int)((k >> 15) & 0x1FFFF);
      int c = flat / NROI;
      int n = (int)((k >> 5) & 0x3FF);
      int row = b * NROI + n;
      float by1, bx1, by2, bx2;
      decode_box(roi + (size_t)row * 4, deltas + ((size_t)row * NCLS + c) * 4,
                 by1, bx1, by2, bx2);
      out_b[ob + 0] = fminf(fmaxf(by1, 0.0f), 1.0f);
      out_b[ob + 1] = fminf(fmaxf(bx1, 0.0f), 1.0f);
      out_b[ob + 2] = fminf(fmaxf(by2, 0.0f), 1.0f);
      out_b[ob + 3] = fminf(fmaxf(bx2, 0.0f), 1.0f);
      out_c[b * MAXKEEP + t] = (float)c;
      out_s[b * MAXKEEP + t] = __uint_as_float((u32)(k >> 32));
    } else {
      out_b[ob + 0] = 0.0f; out_b[ob + 1] = 0.0f;
      out_b[ob + 2] = 0.0f; out_b[ob + 3] = 0.0f;
      out_c[b * MAXKEEP + t] = 0.0f;
      out_s[b * MAXKEEP + t] = 0.0f;
    }
  }
}

extern "C" void kernel_launch(void* const* d_in, const int* in_sizes, int n_in,
                              void* d_out, int out_size, void* d_ws, size_t ws_size,
                              hipStream_t stream) {
  const float* roi    = (const float*)d_in[0];  // [8,1000,4]
  const float* deltas = (const float*)d_in[1];  // [8,1000,324]
  const float* probs  = (const float*)d_in[2];  // [8,1000,81]

  char* ws = (char*)d_ws;
  int* bg         = (int*)(ws);                   // 32000 B
  int* keep_count = (int*)(ws + 32768);           // 2592 B
  int* bhist      = (int*)(ws + 40960);           // 8*8192*4 = 262144 B
  u64* lane_key   = (u64*)(ws + 40960 + 262144);  // 648*200*8 = 1,036,800 B

  float* out_b = (float*)d_out;                 // [8,200,4]
  float* out_c = out_b + NB * MAXKEEP * 4;      // [8,200]
  float* out_s = out_c + NB * MAXKEEP;          // [8,200]

  hipMemsetAsync(bhist, 0, NB * HSIZE * sizeof(int), stream);
  bg_kernel<<<(NB * NROI + 3) / 4, 256, 0, stream>>>(probs, bg);
  gather_nms_kernel<<<NLANE, NT, 0, stream>>>(roi, deltas, probs, bg,
                                              keep_count, lane_key, bhist);
  merge_kernel<<<NB, 512, 0, stream>>>(roi, deltas, keep_count, lane_key, bhist,
                                       out_b, out_c, out_s);
}

// Round 14
// 72.325 us; speedup vs baseline: 2.8071x; 1.3454x over previous
//
#include <hip/hip_runtime.h>

#define NROI 1000
#define NCLS 81
#define NB   8
#define NLANE (NB*NCLS)        // 648 = 8 XCDs * 81
#define MAXM 1024
#define MAXKEEP 200
#define SCORE_T 0.5f
#define NT 512
#define NW 8                   // waves per block
#define HBITS 13
#define HSIZE (1<<HBITS)       // 8192 merge buckets
#define SCAP 1024

typedef unsigned long long u64;
typedef unsigned int u32;

// --- exact-order helpers (no FMA contraction; must match f32 numpy reference) ---

__device__ __forceinline__ void decode_box(const float* __restrict__ roi,
                                           const float* __restrict__ dl,
                                           float& oy1, float& ox1,
                                           float& oy2, float& ox2) {
#pragma clang fp contract(off)
  float y1 = roi[0], x1 = roi[1], y2 = roi[2], x2 = roi[3];
  float h = y2 - y1;
  float w = x2 - x1;
  float cy = y1 + 0.5f * h;
  float cx = x1 + 0.5f * w;
  float d0 = dl[0] * 0.1f;
  float d1 = dl[1] * 0.1f;
  float d2 = dl[2] * 0.2f;
  float d3 = dl[3] * 0.2f;
  float ncy = d0 * h + cy;
  float ncx = d1 * w + cx;
  float nh = expf(d2) * h;
  float nw = expf(d3) * w;
  oy1 = ncy - 0.5f * nh;
  ox1 = ncx - 0.5f * nw;
  oy2 = ncy + 0.5f * nh;
  ox2 = ncx + 0.5f * nw;
}

__device__ __forceinline__ float area_f(float4 bx) {
#pragma clang fp contract(off)
  return (bx.z - bx.x) * (bx.w - bx.y);
}

// EXACT equivalent of: fl32(inter/den) > 0.5 (RNE), den>0 — proof in R6/R7:
// collapses to (inter+inter) > den in plain f32.
__device__ __forceinline__ bool hit_f(float4 bi, float ia, float4 bj, float ja) {
#pragma clang fp contract(off)
  float yy1 = fmaxf(bi.x, bj.x);
  float xx1 = fmaxf(bi.y, bj.y);
  float yy2 = fminf(bi.z, bj.z);
  float xx2 = fminf(bi.w, bj.w);
  float ih = fmaxf(yy2 - yy1, 0.0f);
  float iw = fmaxf(xx2 - xx1, 0.0f);
  float inter = ih * iw;
  float den = ia + ja;
  den = den - inter;
  den = den + 1e-8f;
  return (inter + inter) > den;
}

// key packing: [63:32] score bits, [31:15] (131071-flat) so lower flat wins,
//              [14:5] n (payload only), [4:0] zero. Empty slot = 0.
__device__ __forceinline__ u64 pack_key(u32 sbits, int flat, int n) {
  return ((u64)sbits << 32) | ((u64)(131071 - flat) << 15) | ((u64)n << 5);
}

// --- kernel 1: background rows (argmax over classes == 0), wave per row ---
__global__ __launch_bounds__(256) void bg_kernel(const float* __restrict__ probs,
                                                 int* __restrict__ bg) {
  int row = blockIdx.x * 4 + (threadIdx.x >> 6);
  int lane = threadIdx.x & 63;
  if (row >= NB * NROI) return;
  const float* p = probs + (size_t)row * NCLS;
  float m = -1e30f;
  for (int idx = 1 + lane; idx < NCLS; idx += 64) m = fmaxf(m, p[idx]);
  for (int off = 32; off; off >>= 1) m = fmaxf(m, __shfl_xor(m, off));
  if (lane == 0) bg[row] = (p[0] >= m) ? 1 : 0;  // argmax==0 iff p0 >= all others
}

// --- kernel 2 (fused): gather + counting sort + pipelined NMS (fixpoint resolve) ---
__global__ __launch_bounds__(NT) void gather_nms_kernel(
    const float* __restrict__ roi, const float* __restrict__ deltas,
    const float* __restrict__ probs, const int* __restrict__ bg,
    int* __restrict__ keep_count, u64* __restrict__ lane_key,
    int* __restrict__ bhist) {
  // XCD swizzle: 648 = 8*81; dispatch idx%8 = XCD -> XCD x owns batch x entirely
  int lane = (blockIdx.x % 8) * NCLS + blockIdx.x / 8;
  int b = lane / NCLS, c = lane % NCLS;
  int tid = threadIdx.x;
  int w = tid >> 6, l = tid & 63;

  // smem: [0,16K) sbox; aliases skeyU [0,8K) + skeyB [8K,16K) (dead pre-decode)
  //       [16K,24K) skey (final sorted, live to the end)
  //       [24K,25K) bcnt[256]; [25K,26K) bstart[256]
  __shared__ alignas(16) char smem[26624];
  float4* sbox   = (float4*)smem;
  u64*    skeyU  = (u64*)smem;
  u64*    skeyB  = (u64*)(smem + 8192);
  u64*    skey   = (u64*)(smem + 16384);
  int*    bcnt   = (int*)(smem + 24576);
  int*    bstart = (int*)(smem + 25600);
  __shared__ u64 hmask8[NW][64];   // per-wave row-mask slots (no atomics)
  __shared__ u64 suppm8[NW];       // per-wave suppress ballots
  __shared__ u64 keepmask[16];
  __shared__ int scount, segbase[16];

  if (tid == 0) scount = 0;
  if (tid < 256) bcnt[tid] = 0;
  __syncthreads();

  // --- gather: score > 0.5 && !bg, + 8-bit score histogram (fused) ---
  for (int base_n = 0; base_n < NROI; base_n += NT) {
    int n = base_n + tid;
    bool cand = false;
    float s = 0.0f;
    if (n < NROI) {
      int row = b * NROI + n;
      s = probs[(size_t)row * NCLS + c];
      cand = (s > SCORE_T) && (bg[row] == 0);
    }
    u64 bal = __ballot(cand);
    int wb = 0;
    if (l == 0) wb = atomicAdd(&scount, (int)__popcll(bal));
    wb = __shfl(wb, 0);
    if (cand) {
      int off = (int)__popcll(bal & ((1ull << l) - 1ull));
      u32 sb = __float_as_uint(s);
      skeyU[wb + off] = ((u64)sb << 32) | (u64)(0xFFFFFFFFu - (u32)n);
      // scores in (0.5,1): exponent fixed -> top-8 mantissa bits are monotone
      atomicAdd(&bcnt[(sb >> 15) & 255], 1);
    }
  }
  __syncthreads();
  int M = scount;          // <= 1000
  int nchunks = (M + 63) >> 6;

  // --- descending bucket scan (wave 0): bstart/bcnt = start cursors ---
  if (w == 0) {
    int d0 = 4 * l, d1 = d0 + 1, d2 = d0 + 2, d3 = d0 + 3;
    int c0 = bcnt[255 - d0], c1 = bcnt[255 - d1];
    int c2 = bcnt[255 - d2], c3 = bcnt[255 - d3];
    int t = c0 + c1 + c2 + c3;
    int inc = t;
    for (int off = 1; off < 64; off <<= 1) {
      int v = __shfl_up(inc, off);
      if (l >= off) inc += v;
    }
    int excl = inc - t;
    int s0 = excl, s1 = excl + c0, s2 = excl + c0 + c1, s3 = excl + c0 + c1 + c2;
    bcnt[255 - d0] = s0; bstart[255 - d0] = s0;
    bcnt[255 - d1] = s1; bstart[255 - d1] = s1;
    bcnt[255 - d2] = s2; bstart[255 - d2] = s2;
    bcnt[255 - d3] = s3; bstart[255 - d3] = s3;
  }
  __syncthreads();

  // --- scatter into bucket runs (arrival order within run) ---
  for (int p = tid; p < M; p += NT) {
    u64 k = skeyU[p];
    int bkt = (int)((k >> 47) & 255);
    int pos = atomicAdd(&bcnt[bkt], 1);
    skeyB[pos] = k;
  }
  __syncthreads();

  // --- exact cleanup: global rank = bucket start + #greater in run ---
  for (int p = tid; p < M; p += NT) {
    u64 k = skeyB[p];
    int bkt = (int)((k >> 47) & 255);
    int st = bstart[bkt], en = bcnt[bkt];
    int r = st;
    for (int q = st; q < en; ++q) r += (skeyB[q] > k) ? 1 : 0;  // keys unique
    skey[r] = k;
  }
  if (tid < 16) {            // keep bitmask init: bits p < M set
    int rem = M - (tid << 6);
    keepmask[tid] = (rem >= 64) ? ~0ull : ((rem <= 0) ? 0ull : ((1ull << rem) - 1ull));
  }
  __syncthreads();   // skey sorted; skeyU/skeyB dead -> sbox region free

  // --- prologue: wave 7 decodes chunk 0 into sbox ---
  if (w == 7 && nchunks > 0) {
    u64 k = skey[l];
    int nn = (int)(0xFFFFFFFFu - (u32)(k & 0xFFFFFFFFull));
    int row = b * NROI + ((l < M) ? nn : 0);   // clamp: no OOB global reads
    float by1, bx1, by2, bx2;
    decode_box(roi + (size_t)row * 4, deltas + ((size_t)row * NCLS + c) * 4,
               by1, bx1, by2, bx2);
    sbox[l] = make_float4(by1, bx1, by2, bx2);
  }
  __syncthreads();

  // --- chunked greedy NMS: pipelined decode + fixpoint resolve (2 barriers) ---
  int kc = 0;
  const u64 stridemask = 0x0101010101010101ull << w;  // bits i: i%8 == w
  const u64 low = (1ull << l) - 1ull;
  for (int ck = 0; ck < nchunks; ++ck) {
    int start = ck << 6;
    float4 bj = sbox[start + l];       // own column box (coalesced)
    float ja = area_f(bj);

    // map: wave w computes rows i = 8w..8w+7 vs own column l
    {
      u64 part = 0;
#pragma unroll
      for (int r = 0; r < 8; ++r) {
        int i = (w << 3) + r;
        float4 bi = sbox[start + i];   // broadcast
        float ia = area_f(bi);
        if (hit_f(bi, ia, bj, ja)) part |= (1ull << i);
      }
      hmask8[w][l] = part;             // per-wave slot, no atomics
    }

    // suppress: own box vs kept boxes of ALL prev chunks, bits strided by wave
    {
      bool supp = false;
      for (int q = 0; q < ck; ++q) {
        u64 mq = keepmask[q] & stridemask;
        while (mq) {                   // wave-uniform
          int i = __ffsll((unsigned long long)mq) - 1;
          mq &= mq - 1;
          float4 bi = sbox[(q << 6) + i];   // broadcast
          float ia = area_f(bi);
          supp |= hit_f(bi, ia, bj, ja);
        }
      }
      u64 sb = __ballot(supp);
      if (l == 0) suppm8[w] = sb;      // unconditional (may be 0)
    }

    // wave 7: prefetch-decode chunk ck+1 (latency hidden under suppress/resolve)
    if (w == 7 && ck + 1 < nchunks) {
      int p = ((ck + 1) << 6) + l;
      u64 k = skey[p];
      int nn = (int)(0xFFFFFFFFu - (u32)(k & 0xFFFFFFFFull));
      int row = b * NROI + ((p < M) ? nn : 0);
      float by1, bx1, by2, bx2;
      decode_box(roi + (size_t)row * 4, deltas + ((size_t)row * NCLS + c) * 4,
                 by1, bx1, by2, bx2);
      sbox[p] = make_float4(by1, bx1, by2, bx2);
    }
    __syncthreads();   // B: hmask8, suppm8, next sbox tile all visible

    // resolve: ALL waves redundantly — parallel greedy fixpoint.
    // Exact: und-box l is suppressed iff a KEPT lower box hits it; kept iff NO
    // kept-or-undecided lower box hits it. Lowest und bit always decides.
    u64 rowm = hmask8[0][l] | hmask8[1][l] | hmask8[2][l] | hmask8[3][l]
             | hmask8[4][l] | hmask8[5][l] | hmask8[6][l] | hmask8[7][l];
    u64 sall = suppm8[0] | suppm8[1] | suppm8[2] | suppm8[3]
             | suppm8[4] | suppm8[5] | suppm8[6] | suppm8[7];
    int rem0 = M - start;
    u64 alive = (rem0 >= 64) ? ~0ull : ((rem0 <= 0) ? 0ull : ((1ull << rem0) - 1ull));
    u64 und = alive & ~sall;
    u64 kept = 0;
    while (und) {                      // wave-uniform; ~2-4 rounds typical
      bool isu = (und >> l) & 1;
      bool su = isu && ((rowm & kept & low) != 0ull);
      bool ke = isu && ((rowm & (kept | und) & low) == 0ull);
      u64 sm = __ballot(su);
      u64 km2 = __ballot(ke);
      kept |= km2;
      und &= ~(sm | km2);
    }
    if (tid == 0) keepmask[ck] = kept;
    kc += (int)__popcll(kept);         // identical across all waves
    if (kc >= MAXKEEP) break;          // block-uniform early termination
    __syncthreads();   // A: keepmask[ck] visible; resolve reads done pre-rewrite
  }
  __syncthreads();

  // --- parallel compaction + fused per-batch 13-bit histogram ---
  if (tid < 16) {
    int acc = 0;
    for (int i = 0; i < tid; ++i) acc += (int)__popcll(keepmask[i]);
    segbase[tid] = acc;
  }
  __syncthreads();
  int total = segbase[15] + (int)__popcll(keepmask[15]);
  for (int s = 0; s < 2; ++s) {
    int seg = (w << 1) + s;
    u64 word = keepmask[seg];
    int p = (seg << 6) + l;
    if ((word >> l) & 1) {
      int rank = segbase[seg] + (int)__popcll(word & ((1ull << l) - 1ull));
      if (rank < MAXKEEP) {
        u64 k = skey[p];
        u32 sbits = (u32)(k >> 32);
        int n = (int)(0xFFFFFFFFu - (u32)(k & 0xFFFFFFFFull));
        lane_key[(size_t)lane * MAXKEEP + rank] = pack_key(sbits, c * NROI + p, n);
        atomicAdd(&bhist[b * HSIZE + (int)((sbits >> 10) & (HSIZE - 1))], 1);
      }
    }
  }
  if (tid == 0) keep_count[lane] = min(total, MAXKEEP);
}

// --- kernel 3: per-batch parallel top-200 (radix-select + bitonic), exact order ---
__global__ __launch_bounds__(512) void merge_kernel(
    const float* __restrict__ roi, const float* __restrict__ deltas,
    const int* __restrict__ keep_count, const u64* __restrict__ lane_key,
    const int* __restrict__ bhist,
    float* __restrict__ out_b, float* __restrict__ out_c, float* __restrict__ out_s) {
  int b = blockIdx.x;    // 8 blocks; idx%8 = XCD that produced batch b's keys
  int tid = threadIdx.x;
  int w = tid >> 6, l = tid & 63;

  __shared__ int hist[HSIZE];
  __shared__ int csum[256];
  __shared__ int cnts[NCLS];
  __shared__ int tb_sh, scnt_sh;
  __shared__ u64 surv[SCAP];

  for (int i = tid; i < HSIZE; i += 512) hist[i] = bhist[b * HSIZE + i];
  for (int i = tid; i < NCLS; i += 512) cnts[i] = keep_count[b * NCLS + i];
  if (tid == 0) { tb_sh = 0; scnt_sh = 0; }
  __syncthreads();

  // per-thread 32-bucket partial sums
  int base = tid * 32;
  if (tid < 256) {
    int psum = 0;
    for (int i = 0; i < 32; ++i) psum += hist[base + i];
    csum[tid] = psum;
  }
  __syncthreads();
  // wave-0 parallel suffix scan of the 256 partials (4 per lane, shfl_down)
  if (w == 0) {
    int c0 = csum[4 * l], c1 = csum[4 * l + 1], c2 = csum[4 * l + 2], c3 = csum[4 * l + 3];
    int t = c0 + c1 + c2 + c3;
    int acc = t;
    for (int off = 1; off < 64; off <<= 1) {
      int v = __shfl_down(acc, off);
      if (l + off < 64) acc += v;
    }
    int below = acc - t;               // suffix of lane groups l+1..63
    csum[4 * l + 3] = below + c3;
    csum[4 * l + 2] = below + c3 + c2;
    csum[4 * l + 1] = below + c3 + c2 + c1;
    csum[4 * l + 0] = below + t;       // inclusive suffix from group 4l
  }
  __syncthreads();
  // find tb = max bucket with sufsum >= 200 (0 if total < 200)
  if (tid < 256) {
    int acc = (tid < 255) ? csum[tid + 1] : 0;
    int local_tb = -1;
    for (int i = 31; i >= 0; --i) {
      acc += hist[base + i];
      if (acc >= MAXKEEP && local_tb < 0) local_tb = base + i;
    }
    if (local_tb >= 0) atomicMax(&tb_sh, local_tb);
  }
  __syncthreads();
  int tb = tb_sh;

  // gather survivors (all keys in buckets >= tb; superset of exact top-200)
  for (int s = tid; s < NCLS * MAXKEEP; s += 512) {
    int c = s / MAXKEEP, h = s % MAXKEEP;
    if (h < cnts[c]) {
      u64 k = lane_key[((size_t)(b * NCLS + c)) * MAXKEEP + h];
      u32 sb = (u32)(k >> 32);
      if ((int)((sb >> 10) & (HSIZE - 1)) >= tb) {
        int pos = atomicAdd(&scnt_sh, 1);
        if (pos < SCAP) surv[pos] = k;
      }
    }
  }
  __syncthreads();
  int scnt = min(scnt_sh, SCAP);
  int size = 2;
  while (size < scnt) size <<= 1;
  for (int i = scnt + tid; i < size; i += 512) surv[i] = 0ull;
  __syncthreads();

  // bitonic sort descending by full key (score desc, flat asc)
  for (int k2 = 2; k2 <= size; k2 <<= 1) {
    for (int j = k2 >> 1; j > 0; j >>= 1) {
      for (int i = tid; i < size; i += 512) {
        int ixj = i ^ j;
        if (ixj > i) {
          u64 a = surv[i], bb = surv[ixj];
          bool swp = ((i & k2) == 0) ? (a < bb) : (a > bb);
          if (swp) { surv[i] = bb; surv[ixj] = a; }
        }
      }
      __syncthreads();
    }
  }

  // decode + write top-200 in parallel; zero-fill the rest
  for (int t = tid; t < MAXKEEP; t += 512) {
    size_t ob = ((size_t)b * MAXKEEP + t) * 4;
    if (t < scnt) {
      u64 k = surv[t];
      int flat = 131071 - (int)((k >> 15) & 0x1FFFF);
      int c = flat / NROI;
      int n = (int)((k >> 5) & 0x3FF);
      int row = b * NROI + n;
      float by1, bx1, by2, bx2;
      decode_box(roi + (size_t)row * 4, deltas + ((size_t)row * NCLS + c) * 4,
                 by1, bx1, by2, bx2);
      out_b[ob + 0] = fminf(fmaxf(by1, 0.0f), 1.0f);
      out_b[ob + 1] = fminf(fmaxf(bx1, 0.0f), 1.0f);
      out_b[ob + 2] = fminf(fmaxf(by2, 0.0f), 1.0f);
      out_b[ob + 3] = fminf(fmaxf(bx2, 0.0f), 1.0f);
      out_c[b * MAXKEEP + t] = (float)c;
      out_s[b * MAXKEEP + t] = __uint_as_float((u32)(k >> 32));
    } else {
      out_b[ob + 0] = 0.0f; out_b[ob + 1] = 0.0f;
      out_b[ob + 2] = 0.0f; out_b[ob + 3] = 0.0f;
      out_c[b * MAXKEEP + t] = 0.0f;
      out_s[b * MAXKEEP + t] = 0.0f;
    }
  }
}

extern "C" void kernel_launch(void* const* d_in, const int* in_sizes, int n_in,
                              void* d_out, int out_size, void* d_ws, size_t ws_size,
                              hipStream_t stream) {
  const float* roi    = (const float*)d_in[0];  // [8,1000,4]
  const float* deltas = (const float*)d_in[1];  // [8,1000,324]
  const float* probs  = (const float*)d_in[2];  // [8,1000,81]

  char* ws = (char*)d_ws;
  int* bg         = (int*)(ws);                   // 32000 B
  int* keep_count = (int*)(ws + 32768);           // 2592 B
  int* bhist      = (int*)(ws + 40960);           // 8*8192*4 = 262144 B
  u64* lane_key   = (u64*)(ws + 40960 + 262144);  // 648*200*8 = 1,036,800 B

  float* out_b = (float*)d_out;                 // [8,200,4]
  float* out_c = out_b + NB * MAXKEEP * 4;      // [8,200]
  float* out_s = out_c + NB * MAXKEEP;          // [8,200]

  hipMemsetAsync(bhist, 0, NB * HSIZE * sizeof(int), stream);
  bg_kernel<<<(NB * NROI + 3) / 4, 256, 0, stream>>>(probs, bg);
  gather_nms_kernel<<<NLANE, NT, 0, stream>>>(roi, deltas, probs, bg,
                                              keep_count, lane_key, bhist);
  merge_kernel<<<NB, 512, 0, stream>>>(roi, deltas, keep_count, lane_key, bhist,
                                       out_b, out_c, out_s);
}

// Round 15
// 66.116 us; speedup vs baseline: 3.0707x; 1.0939x over previous
//
#include <hip/hip_runtime.h>

#define NROI 1000
#define NCLS 81
#define NB   8
#define NLANE (NB*NCLS)        // 648 = 8 XCDs * 81
#define MAXM 1024
#define MAXKEEP 200
#define SCORE_T 0.5f
#define NT 512
#define NW 8                   // waves per block
#define HBITS 13
#define HSIZE (1<<HBITS)       // 8192 merge buckets
#define SCAP 1024

typedef unsigned long long u64;
typedef unsigned int u32;

// --- exact-order helpers (no FMA contraction; must match f32 numpy reference) ---

__device__ __forceinline__ void decode_box(const float* __restrict__ roi,
                                           const float* __restrict__ dl,
                                           float& oy1, float& ox1,
                                           float& oy2, float& ox2) {
#pragma clang fp contract(off)
  float y1 = roi[0], x1 = roi[1], y2 = roi[2], x2 = roi[3];
  float h = y2 - y1;
  float w = x2 - x1;
  float cy = y1 + 0.5f * h;
  float cx = x1 + 0.5f * w;
  float d0 = dl[0] * 0.1f;
  float d1 = dl[1] * 0.1f;
  float d2 = dl[2] * 0.2f;
  float d3 = dl[3] * 0.2f;
  float ncy = d0 * h + cy;
  float ncx = d1 * w + cx;
  float nh = expf(d2) * h;
  float nw = expf(d3) * w;
  oy1 = ncy - 0.5f * nh;
  ox1 = ncx - 0.5f * nw;
  oy2 = ncy + 0.5f * nh;
  ox2 = ncx + 0.5f * nw;
}

__device__ __forceinline__ float area_f(float4 bx) {
#pragma clang fp contract(off)
  return (bx.z - bx.x) * (bx.w - bx.y);
}

// EXACT equivalent of: fl32(inter/den) > 0.5 (RNE), den>0 — proof in R6/R7:
// collapses to (inter+inter) > den in plain f32.
__device__ __forceinline__ bool hit_f(float4 bi, float ia, float4 bj, float ja) {
#pragma clang fp contract(off)
  float yy1 = fmaxf(bi.x, bj.x);
  float xx1 = fmaxf(bi.y, bj.y);
  float yy2 = fminf(bi.z, bj.z);
  float xx2 = fminf(bi.w, bj.w);
  float ih = fmaxf(yy2 - yy1, 0.0f);
  float iw = fmaxf(xx2 - xx1, 0.0f);
  float inter = ih * iw;
  float den = ia + ja;
  den = den - inter;
  den = den + 1e-8f;
  return (inter + inter) > den;
}

// key packing: [63:32] score bits, [31:15] (131071-flat) so lower flat wins,
//              [14:5] n (payload only), [4:0] zero. Empty slot = 0.
__device__ __forceinline__ u64 pack_key(u32 sbits, int flat, int n) {
  return ((u64)sbits << 32) | ((u64)(131071 - flat) << 15) | ((u64)n << 5);
}

// --- kernel 1: background rows + bhist zeroing (fold the memset dispatch) ---
__global__ __launch_bounds__(256) void bg_kernel(const float* __restrict__ probs,
                                                 int* __restrict__ bg,
                                                 int* __restrict__ bhist) {
  if (blockIdx.x < 64) {     // zero 8*8192 ints across 64 blocks (4/thread)
    int base = blockIdx.x * 1024 + threadIdx.x;
#pragma unroll
    for (int r = 0; r < 4; ++r) bhist[base + (r << 8)] = 0;
  }
  int row = blockIdx.x * 4 + (threadIdx.x >> 6);
  int lane = threadIdx.x & 63;
  if (row >= NB * NROI) return;
  const float* p = probs + (size_t)row * NCLS;
  float m = -1e30f;
  for (int idx = 1 + lane; idx < NCLS; idx += 64) m = fmaxf(m, p[idx]);
  for (int off = 32; off; off >>= 1) m = fmaxf(m, __shfl_xor(m, off));
  if (lane == 0) bg[row] = (p[0] >= m) ? 1 : 0;  // argmax==0 iff p0 >= all others
}

// --- kernel 2 (fused): gather + counting sort + pipelined NMS (fixpoint resolve) ---
__global__ __launch_bounds__(NT) void gather_nms_kernel(
    const float* __restrict__ roi, const float* __restrict__ deltas,
    const float* __restrict__ probs, const int* __restrict__ bg,
    int* __restrict__ keep_count, u64* __restrict__ lane_key,
    int* __restrict__ bhist) {
  // XCD swizzle: 648 = 8*81; dispatch idx%8 = XCD -> XCD x owns batch x entirely
  int lane = (blockIdx.x % 8) * NCLS + blockIdx.x / 8;
  int b = lane / NCLS, c = lane % NCLS;
  int tid = threadIdx.x;
  int w = tid >> 6, l = tid & 63;

  // smem: [0,16K) sbox; aliases skeyU [0,8K) + skeyB [8K,16K) (dead pre-decode)
  //       [16K,24K) skey (final sorted, live to the end)
  //       [24K,25K) bcnt[256]; [25K,26K) bstart[256]
  __shared__ alignas(16) char smem[26624];
  float4* sbox   = (float4*)smem;
  u64*    skeyU  = (u64*)smem;
  u64*    skeyB  = (u64*)(smem + 8192);
  u64*    skey   = (u64*)(smem + 16384);
  int*    bcnt   = (int*)(smem + 24576);
  int*    bstart = (int*)(smem + 25600);
  __shared__ u64 hmask8[NW][64];   // per-wave row-mask slots (no atomics)
  __shared__ u64 suppm8[NW];       // per-wave suppress ballots
  __shared__ u64 keepmask[16];
  __shared__ int scount, segbase[16];

  if (tid == 0) scount = 0;
  if (tid < 256) bcnt[tid] = 0;
  __syncthreads();

  // --- gather: score > 0.5 && !bg, + 8-bit score histogram (fused) ---
  for (int base_n = 0; base_n < NROI; base_n += NT) {
    int n = base_n + tid;
    bool cand = false;
    float s = 0.0f;
    if (n < NROI) {
      int row = b * NROI + n;
      s = probs[(size_t)row * NCLS + c];
      cand = (s > SCORE_T) && (bg[row] == 0);
    }
    u64 bal = __ballot(cand);
    int wb = 0;
    if (l == 0) wb = atomicAdd(&scount, (int)__popcll(bal));
    wb = __shfl(wb, 0);
    if (cand) {
      int off = (int)__popcll(bal & ((1ull << l) - 1ull));
      u32 sb = __float_as_uint(s);
      skeyU[wb + off] = ((u64)sb << 32) | (u64)(0xFFFFFFFFu - (u32)n);
      // scores in (0.5,1): exponent fixed -> top-8 mantissa bits are monotone
      atomicAdd(&bcnt[(sb >> 15) & 255], 1);
    }
  }
  __syncthreads();
  int M = scount;          // <= 1000
  int nchunks = (M + 63) >> 6;

  // --- descending bucket scan (wave 0): bstart/bcnt = start cursors ---
  if (w == 0) {
    int d0 = 4 * l, d1 = d0 + 1, d2 = d0 + 2, d3 = d0 + 3;
    int c0 = bcnt[255 - d0], c1 = bcnt[255 - d1];
    int c2 = bcnt[255 - d2], c3 = bcnt[255 - d3];
    int t = c0 + c1 + c2 + c3;
    int inc = t;
    for (int off = 1; off < 64; off <<= 1) {
      int v = __shfl_up(inc, off);
      if (l >= off) inc += v;
    }
    int excl = inc - t;
    int s0 = excl, s1 = excl + c0, s2 = excl + c0 + c1, s3 = excl + c0 + c1 + c2;
    bcnt[255 - d0] = s0; bstart[255 - d0] = s0;
    bcnt[255 - d1] = s1; bstart[255 - d1] = s1;
    bcnt[255 - d2] = s2; bstart[255 - d2] = s2;
    bcnt[255 - d3] = s3; bstart[255 - d3] = s3;
  }
  __syncthreads();

  // --- scatter into bucket runs (arrival order within run) ---
  for (int p = tid; p < M; p += NT) {
    u64 k = skeyU[p];
    int bkt = (int)((k >> 47) & 255);
    int pos = atomicAdd(&bcnt[bkt], 1);
    skeyB[pos] = k;
  }
  __syncthreads();

  // --- exact cleanup: global rank = bucket start + #greater in run ---
  for (int p = tid; p < M; p += NT) {
    u64 k = skeyB[p];
    int bkt = (int)((k >> 47) & 255);
    int st = bstart[bkt], en = bcnt[bkt];
    int r = st;
    for (int q = st; q < en; ++q) r += (skeyB[q] > k) ? 1 : 0;  // keys unique
    skey[r] = k;
  }
  if (tid < 16) {            // keep bitmask init: bits p < M set
    int rem = M - (tid << 6);
    keepmask[tid] = (rem >= 64) ? ~0ull : ((rem <= 0) ? 0ull : ((1ull << rem) - 1ull));
  }
  __syncthreads();   // skey sorted; skeyU/skeyB dead -> sbox region free

  // --- prologue: wave 7 decodes chunk 0 into sbox ---
  if (w == 7 && nchunks > 0) {
    u64 k = skey[l];
    int nn = (int)(0xFFFFFFFFu - (u32)(k & 0xFFFFFFFFull));
    int row = b * NROI + ((l < M) ? nn : 0);   // clamp: no OOB global reads
    float by1, bx1, by2, bx2;
    decode_box(roi + (size_t)row * 4, deltas + ((size_t)row * NCLS + c) * 4,
               by1, bx1, by2, bx2);
    sbox[l] = make_float4(by1, bx1, by2, bx2);
  }
  __syncthreads();

  // --- chunked greedy NMS: pipelined decode + fixpoint resolve (2 barriers) ---
  int kc = 0;
  const u64 stridemask = 0x0101010101010101ull << w;  // bits i: i%8 == w
  const u64 low = (1ull << l) - 1ull;
  for (int ck = 0; ck < nchunks; ++ck) {
    int start = ck << 6;
    float4 bj = sbox[start + l];       // own column box (coalesced)
    float ja = area_f(bj);

    // map: wave w computes rows i = 8w..8w+7 vs own column l
    {
      u64 part = 0;
#pragma unroll
      for (int r = 0; r < 8; ++r) {
        int i = (w << 3) + r;
        float4 bi = sbox[start + i];   // broadcast
        float ia = area_f(bi);
        if (hit_f(bi, ia, bj, ja)) part |= (1ull << i);
      }
      hmask8[w][l] = part;             // per-wave slot, no atomics
    }

    // suppress: own box vs kept boxes of ALL prev chunks, bits strided by wave
    {
      bool supp = false;
      for (int q = 0; q < ck; ++q) {
        u64 mq = keepmask[q] & stridemask;
        while (mq) {                   // wave-uniform
          int i = __ffsll((unsigned long long)mq) - 1;
          mq &= mq - 1;
          float4 bi = sbox[(q << 6) + i];   // broadcast
          float ia = area_f(bi);
          supp |= hit_f(bi, ia, bj, ja);
        }
      }
      u64 sb = __ballot(supp);
      if (l == 0) suppm8[w] = sb;      // unconditional (may be 0)
    }

    // wave 7: prefetch-decode chunk ck+1 (latency hidden under suppress/resolve)
    if (w == 7 && ck + 1 < nchunks) {
      int p = ((ck + 1) << 6) + l;
      u64 k = skey[p];
      int nn = (int)(0xFFFFFFFFu - (u32)(k & 0xFFFFFFFFull));
      int row = b * NROI + ((p < M) ? nn : 0);
      float by1, bx1, by2, bx2;
      decode_box(roi + (size_t)row * 4, deltas + ((size_t)row * NCLS + c) * 4,
                 by1, bx1, by2, bx2);
      sbox[p] = make_float4(by1, bx1, by2, bx2);
    }
    __syncthreads();   // B: hmask8, suppm8, next sbox tile all visible

    // resolve: ALL waves redundantly — parallel greedy fixpoint.
    // Exact: und-box l is suppressed iff a KEPT lower box hits it; kept iff NO
    // kept-or-undecided lower box hits it. Lowest und bit always decides.
    u64 rowm = hmask8[0][l] | hmask8[1][l] | hmask8[2][l] | hmask8[3][l]
             | hmask8[4][l] | hmask8[5][l] | hmask8[6][l] | hmask8[7][l];
    u64 sall = suppm8[0] | suppm8[1] | suppm8[2] | suppm8[3]
             | suppm8[4] | suppm8[5] | suppm8[6] | suppm8[7];
    int rem0 = M - start;
    u64 alive = (rem0 >= 64) ? ~0ull : ((rem0 <= 0) ? 0ull : ((1ull << rem0) - 1ull));
    u64 und = alive & ~sall;
    u64 kept = 0;
    while (und) {                      // wave-uniform; ~2-4 rounds typical
      bool isu = (und >> l) & 1;
      bool su = isu && ((rowm & kept & low) != 0ull);
      bool ke = isu && ((rowm & (kept | und) & low) == 0ull);
      u64 sm = __ballot(su);
      u64 km2 = __ballot(ke);
      kept |= km2;
      und &= ~(sm | km2);
    }
    if (tid == 0) keepmask[ck] = kept;
    kc += (int)__popcll(kept);         // identical across all waves
    if (kc >= MAXKEEP) break;          // block-uniform early termination
    __syncthreads();   // A: keepmask[ck] visible; resolve reads done pre-rewrite
  }
  __syncthreads();

  // --- parallel compaction + fused per-batch 13-bit histogram ---
  if (tid < 16) {
    int acc = 0;
    for (int i = 0; i < tid; ++i) acc += (int)__popcll(keepmask[i]);
    segbase[tid] = acc;
  }
  __syncthreads();
  int total = segbase[15] + (int)__popcll(keepmask[15]);
  for (int s = 0; s < 2; ++s) {
    int seg = (w << 1) + s;
    u64 word = keepmask[seg];
    int p = (seg << 6) + l;
    if ((word >> l) & 1) {
      int rank = segbase[seg] + (int)__popcll(word & ((1ull << l) - 1ull));
      if (rank < MAXKEEP) {
        u64 k = skey[p];
        u32 sbits = (u32)(k >> 32);
        int n = (int)(0xFFFFFFFFu - (u32)(k & 0xFFFFFFFFull));
        lane_key[(size_t)lane * MAXKEEP + rank] = pack_key(sbits, c * NROI + p, n);
        atomicAdd(&bhist[b * HSIZE + (int)((sbits >> 10) & (HSIZE - 1))], 1);
      }
    }
  }
  if (tid == 0) keep_count[lane] = min(total, MAXKEEP);
}

// --- kernel 3: per-batch rank-direct top-200 (histogram ranks; no sort) ---
__global__ __launch_bounds__(512) void merge_kernel(
    const float* __restrict__ roi, const float* __restrict__ deltas,
    const int* __restrict__ keep_count, const u64* __restrict__ lane_key,
    const int* __restrict__ bhist,
    float* __restrict__ out_b, float* __restrict__ out_c, float* __restrict__ out_s) {
  int b = blockIdx.x;    // 8 blocks; idx%8 = XCD that produced batch b's keys
  int tid = threadIdx.x;
  int w = tid >> 6, l = tid & 63;

  __shared__ int hist[HSIZE];      // counts (kept intact)
  __shared__ int hsuf[HSIZE];      // suffix-exclusive rank base per bucket
  __shared__ int hcur[HSIZE];      // scatter cursors (copy of hsuf)
  __shared__ int csum[256];
  __shared__ int cnts[NCLS];
  __shared__ int total_sh, scnt_sh;
  __shared__ u64 surv[SCAP];

  for (int i = tid; i < HSIZE; i += 512) hist[i] = bhist[b * HSIZE + i];
  for (int i = tid; i < NCLS; i += 512) cnts[i] = keep_count[b * NCLS + i];
  if (tid == 0) scnt_sh = 0;
  // zero-init all output slots (overwritten by winners after barriers)
  for (int t = tid; t < MAXKEEP; t += 512) {
    size_t ob = ((size_t)b * MAXKEEP + t) * 4;
    out_b[ob + 0] = 0.0f; out_b[ob + 1] = 0.0f;
    out_b[ob + 2] = 0.0f; out_b[ob + 3] = 0.0f;
    out_c[b * MAXKEEP + t] = 0.0f;
    out_s[b * MAXKEEP + t] = 0.0f;
  }
  __syncthreads();

  // per-group sums (256 groups of 32 buckets)
  if (tid < 256) {
    int base = tid * 32;
    int psum = 0;
    for (int i = 0; i < 32; ++i) psum += hist[base + i];
    csum[tid] = psum;
  }
  __syncthreads();
  // wave 0: suffix-EXCLUSIVE scan over groups (higher group = higher score)
  if (w == 0) {
    int g0 = 4 * l;
    int c0 = csum[g0], c1 = csum[g0 + 1], c2 = csum[g0 + 2], c3 = csum[g0 + 3];
    int t = c0 + c1 + c2 + c3;
    int acc = t;
    for (int off = 1; off < 64; off <<= 1) {
      int v = __shfl_down(acc, off);
      if (l + off < 64) acc += v;
    }                                  // acc = suffix-inclusive from lane l
    if (l == 0) total_sh = acc;        // total kept keys in batch
    int above = acc - t;               // keys in lanes > l (higher groups)
    csum[g0 + 3] = above;              // suffix-exclusive of group g0+3
    csum[g0 + 2] = above + c3;
    csum[g0 + 1] = above + c3 + c2;
    csum[g0 + 0] = above + c3 + c2 + c1;
  }
  __syncthreads();
  // per-bucket suffix-exclusive rank base (walk each group from top bucket)
  if (tid < 256) {
    int base = tid * 32;
    int acc = csum[tid];
    for (int i = 31; i >= 0; --i) {
      hsuf[base + i] = acc;
      hcur[base + i] = acc;
      acc += hist[base + i];
    }
  }
  __syncthreads();
  int total = total_sh;
  int valid = (total < MAXKEEP) ? total : MAXKEEP;

  // scatter survivors into rank-space slots (buckets whose base < 200)
  for (int s = tid; s < NCLS * MAXKEEP; s += 512) {
    int c = s / MAXKEEP, h = s % MAXKEEP;
    if (h < cnts[c]) {
      u64 k = lane_key[((size_t)(b * NCLS + c)) * MAXKEEP + h];
      int bkt = (int)((k >> 42) & (HSIZE - 1));
      if (hsuf[bkt] < MAXKEEP) {
        int pos = atomicAdd(&hcur[bkt], 1);
        if (pos < SCAP) { surv[pos] = k; atomicAdd(&scnt_sh, 1); }
      }
    }
  }
  __syncthreads();
  int scnt = min(scnt_sh, SCAP);

  // rank-fix within bucket runs (~1-3 keys) + decode + direct write
  for (int p = tid; p < scnt; p += 512) {
    u64 k = surv[p];
    int bkt = (int)((k >> 42) & (HSIZE - 1));
    int st = hsuf[bkt];
    int en = st + hist[bkt];
    if (en > SCAP) en = SCAP;
    int r = st;
    for (int q = st; q < en; ++q) r += (surv[q] > k) ? 1 : 0;  // keys unique
    if (r < valid) {
      int flat = 131071 - (int)((k >> 15) & 0x1FFFF);
      int c = flat / NROI;
      int n = (int)((k >> 5) & 0x3FF);
      int row = b * NROI + n;
      float by1, bx1, by2, bx2;
      decode_box(roi + (size_t)row * 4, deltas + ((size_t)row * NCLS + c) * 4,
                 by1, bx1, by2, bx2);
      size_t ob = ((size_t)b * MAXKEEP + r) * 4;
      out_b[ob + 0] = fminf(fmaxf(by1, 0.0f), 1.0f);
      out_b[ob + 1] = fminf(fmaxf(bx1, 0.0f), 1.0f);
      out_b[ob + 2] = fminf(fmaxf(by2, 0.0f), 1.0f);
      out_b[ob + 3] = fminf(fmaxf(bx2, 0.0f), 1.0f);
      out_c[b * MAXKEEP + r] = (float)c;
      out_s[b * MAXKEEP + r] = __uint_as_float((u32)(k >> 32));
    }
  }
}

extern "C" void kernel_launch(void* const* d_in, const int* in_sizes, int n_in,
                              void* d_out, int out_size, void* d_ws, size_t ws_size,
                              hipStream_t stream) {
  const float* roi    = (const float*)d_in[0];  // [8,1000,4]
  const float* deltas = (const float*)d_in[1];  // [8,1000,324]
  const float* probs  = (const float*)d_in[2];  // [8,1000,81]

  char* ws = (char*)d_ws;
  int* bg         = (int*)(ws);                   // 32000 B
  int* keep_count = (int*)(ws + 32768);           // 2592 B
  int* bhist      = (int*)(ws + 40960);           // 8*8192*4 = 262144 B
  u64* lane_key   = (u64*)(ws + 40960 + 262144);  // 648*200*8 = 1,036,800 B

  float* out_b = (float*)d_out;                 // [8,200,4]
  float* out_c = out_b + NB * MAXKEEP * 4;      // [8,200]
  float* out_s = out_c + NB * MAXKEEP;          // [8,200]

  bg_kernel<<<(NB * NROI + 3) / 4, 256, 0, stream>>>(probs, bg, bhist);
  gather_nms_kernel<<<NLANE, NT, 0, stream>>>(roi, deltas, probs, bg,
                                              keep_count, lane_key, bhist);
  merge_kernel<<<NB, 512, 0, stream>>>(roi, deltas, keep_count, lane_key, bhist,
                                       out_b, out_c, out_s);
}